// Round 3
// baseline (56767.255 us; speedup 1.0000x reference)
//
#include <hip/hip_runtime.h>

// ---------------------------------------------------------------------------
// MLP -> 2-layer LSTM scan (T=256) -> MLP head, MI355X gfx950.
// R3: WEIGHT-STATIONARY. 32 groups x 8 CUs; CU owns 16 h-cols; all weights
// register-resident (Wc 64 VGPR/wave, fc 56 VGPR/wave). Per-step cross-CU
// h1/h2/x exchange via ws (parity slots + value-encoded release/acquire
// flags). fc(t+1) row-split across group, computed in exchange-wait windows.
// Cooperative launch guarantees co-residency of all 256 blocks.
// ---------------------------------------------------------------------------

typedef unsigned short u16;
typedef short bf16x8 __attribute__((ext_vector_type(8)));
typedef float f32x4 __attribute__((ext_vector_type(4)));

#define MFMA16(a, b, c) __builtin_amdgcn_mfma_f32_16x16x32_bf16((a), (b), (c), 0, 0, 0)

#define GLOAD_LDS(gp, lp) __builtin_amdgcn_global_load_lds( \
    (const __attribute__((address_space(1))) unsigned int*)(const void*)(gp), \
    (__attribute__((address_space(3))) unsigned int*)(void*)(lp), 16, 0, 0)

__device__ __forceinline__ u16 f2bf(float f) {
  union { float f; unsigned u; } v; v.f = f;
  return (u16)((v.u + 0x7FFFu + ((v.u >> 16) & 1u)) >> 16);  // RNE
}
__device__ __forceinline__ float fsig(float x) { return 1.0f / (1.0f + __expf(-x)); }
__device__ __forceinline__ float ftanh(float x) { return 2.0f / (1.0f + __expf(-2.0f * x)) - 1.0f; }

// ---- LDS index helpers (u16 units), all 2-way-conflict swizzled ----------
// H1/H2: [8 cb(=src CU)][128 r][2 half][8 e]
__device__ __forceinline__ int hidx(int r, int k) {
  return ((k >> 4) << 11) + (r << 4) + ((((k >> 3) & 1) ^ ((r >> 2) & 1)) << 3) + (k & 7);
}
// XB: [8 rslice(=src CU)][16 rl][8 cb][2 half][8 e]
__device__ __forceinline__ int xidx(int r, int k) {
  int rl = r & 15;
  return ((r >> 4) << 11) + (rl << 7) + (((k >> 4) ^ (rl & 3)) << 4) +
         ((((k >> 3) & 1) ^ ((rl >> 2) & 1)) << 3) + (k & 7);
}
// SEQ slice: [16 rl][4 cb][2 half][8 e]
__device__ __forceinline__ int sidx(int rl, int k) {
  return (rl << 6) + (((k >> 4) ^ (rl & 3)) << 4) +
         ((((k >> 3) & 1) ^ ((rl >> 2) & 1)) << 3) + (k & 7);
}
// F1 slice: [16 rl][16 cb][2 half][8 e]
__device__ __forceinline__ int f1idx(int rl, int k) {
  return (rl << 8) + (((k >> 4) ^ (rl & 3)) << 4) +
         ((((k >> 3) & 1) ^ ((rl >> 2) & 1)) << 3) + (k & 7);
}
// F2 slice: [16 rl][8 cb][2 half][8 e]
__device__ __forceinline__ int f2idx(int rl, int k) {
  return (rl << 7) + (((k >> 4) ^ (rl & 3)) << 4) +
         ((((k >> 3) & 1) ^ ((rl >> 2) & 1)) << 3) + (k & 7);
}

// ---- ws layout ------------------------------------------------------------
// u16 image [0..386048):
//   WC    @0       (((cuj*4+gc)*2+cell)*8+kt)*512 + lane*8 + e
//   W1    @262144  (tile*2+kt)*512 ...   tile 0..15, kt 0..1
//   W2    @278528  (tile*8+kt)*512       tile 0..7,  kt 0..7
//   W3    @311296  (tile*4+kt)*512       tile 0..7,  kt 0..3
//   WO1   @327680  (tile*4+kt)*512       tile 0..7,  kt 0..3
//   WO2   @344064  (tile*4+kt)*512       tile 0..15, kt 0..3
//   WO3   @376832  (tile*8+kt)*512       tile 0..1,  kt 0..7
//   bs1 f32 @f32-idx 192512, bs2 @193024
// EXH @byte 1048576: [g32][cell2][par2][j8] x 4096 B
// EXX @byte 5242880: [g32][par2][j8] x 4096 B
// FLH @byte 7340032: u32 [g32][cell2][j8];  FLX @7342080: u32 [g32][j8]
#define EXH_OFF 1048576u
#define EXX_OFF 5242880u
#define FLH_OFF 7340032u
#define FLX_OFF 7342080u

__global__ void prep_kernel(const float* __restrict__ Wih1, const float* __restrict__ Whh1,
                            const float* __restrict__ bih1, const float* __restrict__ bhh1,
                            const float* __restrict__ Wih2, const float* __restrict__ Whh2,
                            const float* __restrict__ bih2, const float* __restrict__ bhh2,
                            const float* __restrict__ W_in1, const float* __restrict__ W_in2,
                            const float* __restrict__ W_in3,
                            const float* __restrict__ W_out1, const float* __restrict__ W_out2,
                            const float* __restrict__ W_out3,
                            u16* __restrict__ ws) {
  const int N_total = 386048;
  int stride = gridDim.x * blockDim.x;
  for (int idx = blockIdx.x * blockDim.x + threadIdx.x; idx < N_total; idx += stride) {
    if (idx < 385024) {
      int e = idx & 7, lane = (idx >> 3) & 63;
      int lr = lane & 15, lg = lane >> 4;
      float v;
      if (idx < 262144) {                      // WC
        int kt = (idx >> 9) & 7, cell = (idx >> 12) & 1;
        int gcc = (idx >> 13) & 3, cuj = idx >> 15;
        int row = gcc * 128 + cuj * 16 + lr;
        int k = kt * 32 + lg * 8 + e;
        const float* Wih = cell ? Wih2 : Wih1;
        const float* Whh = cell ? Whh2 : Whh1;
        v = (k < 128) ? Wih[row * 128 + k] : Whh[row * 128 + (k - 128)];
      } else if (idx < 278528) {               // W1
        int lo = idx - 262144; int kt = (lo >> 9) & 1, tile = lo >> 10;
        v = W_in1[(tile * 16 + lr) * 64 + kt * 32 + lg * 8 + e];
      } else if (idx < 311296) {               // W2
        int lo = idx - 278528; int kt = (lo >> 9) & 7, tile = lo >> 12;
        v = W_in2[(tile * 16 + lr) * 256 + kt * 32 + lg * 8 + e];
      } else if (idx < 327680) {               // W3
        int lo = idx - 311296; int kt = (lo >> 9) & 3, tile = lo >> 11;
        v = W_in3[(tile * 16 + lr) * 128 + kt * 32 + lg * 8 + e];
      } else if (idx < 344064) {               // WO1
        int lo = idx - 327680; int kt = (lo >> 9) & 3, tile = lo >> 11;
        v = W_out1[(tile * 16 + lr) * 128 + kt * 32 + lg * 8 + e];
      } else if (idx < 376832) {               // WO2
        int lo = idx - 344064; int kt = (lo >> 9) & 3, tile = lo >> 11;
        v = W_out2[(tile * 16 + lr) * 128 + kt * 32 + lg * 8 + e];
      } else {                                 // WO3
        int lo = idx - 376832; int kt = (lo >> 9) & 7, tile = lo >> 12;
        v = W_out3[(tile * 16 + lr) * 256 + kt * 32 + lg * 8 + e];
      }
      ws[idx] = f2bf(v);
    } else if (idx < 385536) {
      int i = idx - 385024;
      ((float*)ws)[192512 + i] = bih1[i] + bhh1[i];
    } else {
      int i = idx - 385536;
      ((float*)ws)[193024 + i] = bih2[i] + bhh2[i];
    }
  }
}

__global__ __launch_bounds__(512, 1)
void scan_kernel(const float* __restrict__ seq,
                 const float* __restrict__ h1_in, const float* __restrict__ c1_in,
                 const float* __restrict__ h2_in, const float* __restrict__ c2_in,
                 const float* __restrict__ b_in1, const float* __restrict__ b_in2,
                 const float* __restrict__ b_in3,
                 const float* __restrict__ b_out1, const float* __restrict__ b_out2,
                 const float* __restrict__ b_out3,
                 u16* __restrict__ wsp, float* __restrict__ out) {
  __shared__ u16 H1[16384], H2[16384], XBs[16384];   // 32 KB each
  __shared__ float GB[8192];                          // 32 KB [128][4 gate][16 c]
  __shared__ u16 F1s[4096], F2s[2048], SEQs[1024];   // 8/4/2 KB

  const int tid = threadIdx.x;
  const int wid = tid >> 6, lane = tid & 63;
  const int lr = lane & 15, lg = lane >> 4;
  const int bid = blockIdx.x;
  const int xcd = bid & 7, ii = bid >> 3;
  const int g = xcd * 4 + (ii >> 3);   // group 0..31
  const int j = ii & 7;                // member 0..7 (owns h-cols [16j,16j+16))
  const int b0 = g * 128;
  const int gc = wid & 3, rh = wid >> 2;
  const int ec = tid & 15;             // ew column

  unsigned* FLH = (unsigned*)((char*)wsp + FLH_OFF);
  unsigned* FLX = (unsigned*)((char*)wsp + FLX_OFF);

  // ---- register-resident weights ----
  bf16x8 wc1[8], wc2[8];
#pragma unroll
  for (int kt = 0; kt < 8; ++kt) {
    wc1[kt] = *(const bf16x8*)(wsp + (((j * 4 + gc) * 2 + 0) * 8 + kt) * 512 + lane * 8);
    wc2[kt] = *(const bf16x8*)(wsp + (((j * 4 + gc) * 2 + 1) * 8 + kt) * 512 + lane * 8);
  }
  bf16x8 w1f[2][2];
#pragma unroll
  for (int ts = 0; ts < 2; ++ts)
#pragma unroll
    for (int kt = 0; kt < 2; ++kt)
      w1f[ts][kt] = *(const bf16x8*)(wsp + 262144 + ((wid + ts * 8) * 2 + kt) * 512 + lane * 8);
  bf16x8 w2f[8];
#pragma unroll
  for (int kt = 0; kt < 8; ++kt)
    w2f[kt] = *(const bf16x8*)(wsp + 278528 + (wid * 8 + kt) * 512 + lane * 8);
  bf16x8 w3f[4];
#pragma unroll
  for (int kt = 0; kt < 4; ++kt)
    w3f[kt] = *(const bf16x8*)(wsp + 311296 + (wid * 4 + kt) * 512 + lane * 8);

  // ---- biases ----
  const float* bsp = (const float*)wsp;
  float bc1[4], bc2[4];
#pragma unroll
  for (int gt = 0; gt < 4; ++gt) {
    bc1[gt] = bsp[192512 + gt * 128 + j * 16 + ec];
    bc2[gt] = bsp[193024 + gt * 128 + j * 16 + ec];
  }
  float bL1[2] = { b_in1[wid * 16 + lr], b_in1[(wid + 8) * 16 + lr] };
  float bL2 = b_in2[wid * 16 + lr];
  float bL3 = b_in3[wid * 16 + lr];

  // ---- c-state: thread owns (r = s*32 + tid>>4, col = j*16+ec), s=0..3 ----
  float cs1[4], cs2[4];
#pragma unroll
  for (int s = 0; s < 4; ++s) {
    int r = s * 32 + (tid >> 4);
    cs1[s] = c1_in[(size_t)(b0 + r) * 128 + j * 16 + ec];
    cs2[s] = c2_in[(size_t)(b0 + r) * 128 + j * 16 + ec];
  }
  // ---- H init (full h1_in/h2_in for this group's rows) ----
#pragma unroll
  for (int m = 0; m < 32; ++m) {
    int idx = m * 512 + tid;
    int r = idx >> 7, k = idx & 127;
    int hi = hidx(r, k);
    H1[hi] = f2bf(h1_in[(size_t)(b0 + r) * 128 + k]);
    H2[hi] = f2bf(h2_in[(size_t)(b0 + r) * 128 + k]);
  }

  // ---- seq prefetch regs (rl = tid>>5, pos = tid&31 -> k = 2*pos) ----
  float2 sq;
  const int srl = tid >> 5, spos = tid & 31;
  auto seq_issue = [&](int t1) {
    sq = *(const float2*)(seq + ((size_t)(b0 + j * 16 + srl) * 256 + t1) * 64 + spos * 2);
  };
  auto seq_stage = [&]() {
    int k = spos * 2;
    int idx = sidx(srl, k);
    u16 two[2] = { f2bf(sq.x), f2bf(sq.y) };
    *(unsigned*)&SEQs[idx] = *(const unsigned*)two;
  };

  // ---- fc layers (row-split: this CU computes rows [j*16, j*16+16)) ----
  auto fcL1 = [&]() {
    f32x4 a1[2] = { f32x4{0,0,0,0}, f32x4{0,0,0,0} };
#pragma unroll
    for (int kt = 0; kt < 2; ++kt) {
      bf16x8 a = *(const bf16x8*)&SEQs[sidx(lr, kt * 32 + lg * 8)];
      a1[0] = MFMA16(a, w1f[0][kt], a1[0]);
      a1[1] = MFMA16(a, w1f[1][kt], a1[1]);
    }
#pragma unroll
    for (int ts = 0; ts < 2; ++ts)
#pragma unroll
      for (int jj = 0; jj < 4; ++jj) {
        int rl = lg * 4 + jj, k = (wid + ts * 8) * 16 + lr;
        F1s[f1idx(rl, k)] = f2bf(fmaxf(a1[ts][jj] + bL1[ts], 0.f));
      }
  };
  auto fcL2 = [&]() {
    f32x4 a2 = {0, 0, 0, 0};
#pragma unroll
    for (int kt = 0; kt < 8; ++kt) {
      bf16x8 a = *(const bf16x8*)&F1s[f1idx(lr, kt * 32 + lg * 8)];
      a2 = MFMA16(a, w2f[kt], a2);
    }
#pragma unroll
    for (int jj = 0; jj < 4; ++jj) {
      int rl = lg * 4 + jj, k = wid * 16 + lr;
      F2s[f2idx(rl, k)] = f2bf(fmaxf(a2[jj] + bL2, 0.f));
    }
  };
  auto fcL3 = [&](u16* exx) {
    f32x4 a3 = {0, 0, 0, 0};
#pragma unroll
    for (int kt = 0; kt < 4; ++kt) {
      bf16x8 a = *(const bf16x8*)&F2s[f2idx(lr, kt * 32 + lg * 8)];
      a3 = MFMA16(a, w3f[kt], a3);
    }
#pragma unroll
    for (int jj = 0; jj < 4; ++jj) {
      int rl = lg * 4 + jj, k = wid * 16 + lr;
      u16 xb = f2bf(fmaxf(a3[jj] + bL3, 0.f));
      int xin = xidx(j * 16 + rl, k);
      XBs[xin] = xb;
      exx[xin - (j << 11)] = xb;
    }
  };

  // ---- GB write / elementwise ----
  auto gbw = [&](f32x4 (&acc)[4]) {
#pragma unroll
    for (int rt = 0; rt < 4; ++rt)
#pragma unroll
      for (int jj = 0; jj < 4; ++jj) {
        int r = (rh * 4 + rt) * 16 + lg * 4 + jj;
        GB[r * 64 + gc * 16 + lr] = acc[rt][jj];
      }
  };
  auto ew = [&](const float* bc, float (&cs)[4], u16* Hdst, u16* exh) {
#pragma unroll
    for (int s = 0; s < 4; ++s) {
      int r = s * 32 + (tid >> 4);
      float gi = GB[r * 64 + 0 * 16 + ec] + bc[0];
      float gf = GB[r * 64 + 1 * 16 + ec] + bc[1];
      float gg = GB[r * 64 + 2 * 16 + ec] + bc[2];
      float go = GB[r * 64 + 3 * 16 + ec] + bc[3];
      float cn = fsig(gf) * cs[s] + fsig(gi) * ftanh(gg);
      cs[s] = cn;
      u16 hb = f2bf(fsig(go) * ftanh(cn));
      int hin = hidx(r, j * 16 + ec);
      Hdst[hin] = hb;
      exh[hin - (j << 11)] = hb;
    }
  };

  // ---- flag helpers ----
  auto spinf = [&](unsigned* base, unsigned want) {
    if (tid < 7) {
      int p = tid + (tid >= j);
      while (__hip_atomic_load(base + p, __ATOMIC_ACQUIRE, __HIP_MEMORY_SCOPE_AGENT) < want)
        __builtin_amdgcn_s_sleep(1);
    }
    __syncthreads();
    __threadfence();   // agent-scope acquire for all threads before pulls
  };
  auto postf = [&](unsigned* slot, unsigned val) {
    // callers: per-thread s_waitcnt vmcnt(0) + __syncthreads() already done
    if (tid == 0) __hip_atomic_store(slot, val, __ATOMIC_RELEASE, __HIP_MEMORY_SCOPE_AGENT);
  };
  auto pull_h = [&](u16* Hdst, const char* exbase) {
    if (wid < 7) {
      int p = wid + (wid >= j);
      const u16* src = (const u16*)(exbase + p * 4096);
#pragma unroll
      for (int i = 0; i < 4; ++i)
        GLOAD_LDS(src + i * 512 + lane * 8, &Hdst[p * 2048 + i * 512]);
    }
    asm volatile("s_waitcnt vmcnt(0)" ::: "memory");
    __syncthreads();
  };

  // ================= prologue: fc(0) =================
  seq_issue(0);
  __syncthreads();                      // H init visible
  asm volatile("s_waitcnt vmcnt(0)" ::: "memory");
  seq_stage();
  __syncthreads();
  fcL1();
  __syncthreads();
  fcL2();
  __syncthreads();
  {
    u16* exx0 = (u16*)((char*)wsp + EXX_OFF + ((g * 2 + 0) * 8 + j) * 4096);
    fcL3(exx0);
  }
  asm volatile("s_waitcnt vmcnt(0)" ::: "memory");
  __syncthreads();
  __threadfence();
  postf(FLX + g * 8 + j, 1u);

  // ================= scan =================
  for (int t = 0; t < 256; ++t) {
    const int par = t & 1;
    const char* exhb1 = (char*)wsp + EXH_OFF + (((g * 2 + 0) * 2 + par) * 8) * 4096;
    const char* exhb2 = (char*)wsp + EXH_OFF + (((g * 2 + 1) * 2 + par) * 8) * 4096;
    const char* exxb  = (char*)wsp + EXX_OFF + ((g * 2 + par) * 8) * 4096;

    // -- pull x(t) --
    spinf(FLX + g * 8, (unsigned)(t + 1));
    if (wid < 7) {
      int p = wid + (wid >= j);
      const u16* src = (const u16*)(exxb + p * 4096);
#pragma unroll
      for (int i = 0; i < 4; ++i)
        GLOAD_LDS(src + i * 512 + lane * 8, &XBs[p * 2048 + i * 512]);
    }
    asm volatile("s_waitcnt vmcnt(0)" ::: "memory");
    __syncthreads();

    // -- cell1 GEMM: A = [x_t | h1(t-1)] --
    f32x4 acc1[4] = { f32x4{0,0,0,0}, f32x4{0,0,0,0}, f32x4{0,0,0,0}, f32x4{0,0,0,0} };
#pragma unroll
    for (int kt = 0; kt < 4; ++kt) {
      int k0 = kt * 32 + lg * 8;
#pragma unroll
      for (int rt = 0; rt < 4; ++rt) {
        int r = (rh * 4 + rt) * 16 + lr;
        bf16x8 a = *(const bf16x8*)&XBs[xidx(r, k0)];
        acc1[rt] = MFMA16(a, wc1[kt], acc1[rt]);
      }
    }
#pragma unroll
    for (int kt = 0; kt < 4; ++kt) {
      int k0 = kt * 32 + lg * 8;
#pragma unroll
      for (int rt = 0; rt < 4; ++rt) {
        int r = (rh * 4 + rt) * 16 + lr;
        bf16x8 a = *(const bf16x8*)&H1[hidx(r, k0)];
        acc1[rt] = MFMA16(a, wc1[4 + kt], acc1[rt]);
      }
    }
    if (t < 255) seq_issue(t + 1);
    __syncthreads();                    // cell1 H1-reads done before ew1 writes
    gbw(acc1);
    __syncthreads();
    ew(bc1, cs1, H1, (u16*)(exhb1 + j * 4096));
    asm volatile("s_waitcnt vmcnt(0)" ::: "memory");
    __syncthreads();
    __threadfence();
    postf(FLH + (g * 2 + 0) * 8 + j, (unsigned)(t + 1));

    // -- fc(t+1) L1 (exchange-wait filler) --
    if (t < 255) {
      seq_stage();                      // sq arrived (vmcnt(0) above)
      __syncthreads();
      fcL1();
    }
    __syncthreads();

    // -- pull h1(t) --
    spinf(FLH + (g * 2 + 0) * 8, (unsigned)(t + 1));
    pull_h(H1, exhb1);

    // -- cell2 GEMM: A = [h1(t) | h2(t-1)] --
    f32x4 acc2[4] = { f32x4{0,0,0,0}, f32x4{0,0,0,0}, f32x4{0,0,0,0}, f32x4{0,0,0,0} };
#pragma unroll
    for (int kt = 0; kt < 4; ++kt) {
      int k0 = kt * 32 + lg * 8;
#pragma unroll
      for (int rt = 0; rt < 4; ++rt) {
        int r = (rh * 4 + rt) * 16 + lr;
        bf16x8 a = *(const bf16x8*)&H1[hidx(r, k0)];
        acc2[rt] = MFMA16(a, wc2[kt], acc2[rt]);
      }
    }
#pragma unroll
    for (int kt = 0; kt < 4; ++kt) {
      int k0 = kt * 32 + lg * 8;
#pragma unroll
      for (int rt = 0; rt < 4; ++rt) {
        int r = (rh * 4 + rt) * 16 + lr;
        bf16x8 a = *(const bf16x8*)&H2[hidx(r, k0)];
        acc2[rt] = MFMA16(a, wc2[4 + kt], acc2[rt]);
      }
    }
    __syncthreads();
    gbw(acc2);
    __syncthreads();
    ew(bc2, cs2, H2, (u16*)(exhb2 + j * 4096));
    asm volatile("s_waitcnt vmcnt(0)" ::: "memory");
    __syncthreads();
    __threadfence();
    postf(FLH + (g * 2 + 1) * 8 + j, (unsigned)(t + 1));

    // -- fc(t+1) L2/L3 + x-exchange post (filler) --
    if (t < 255) {
      fcL2();
      __syncthreads();
      const char* exxn = (char*)wsp + EXX_OFF + ((g * 2 + ((t + 1) & 1)) * 8) * 4096;
      fcL3((u16*)(exxn + j * 4096));
      asm volatile("s_waitcnt vmcnt(0)" ::: "memory");
      __syncthreads();
      __threadfence();
      postf(FLX + g * 8 + j, (unsigned)(t + 2));
    }

    // -- pull h2(t) --
    spinf(FLH + (g * 2 + 1) * 8, (unsigned)(t + 1));
    pull_h(H2, exhb2);
  }

  // ================= head (own 16 rows: r = j*16 + ..) =================
  {
    f32x4 y1 = {0, 0, 0, 0};
#pragma unroll
    for (int kt = 0; kt < 4; ++kt) {
      bf16x8 a = *(const bf16x8*)&H2[hidx(j * 16 + lr, kt * 32 + lg * 8)];
      bf16x8 b = *(const bf16x8*)(wsp + 327680 + (wid * 4 + kt) * 512 + lane * 8);
      y1 = MFMA16(a, b, y1);
    }
    float bo1 = b_out1[wid * 16 + lr];
#pragma unroll
    for (int jj = 0; jj < 4; ++jj)
      F2s[f2idx(lg * 4 + jj, wid * 16 + lr)] = f2bf(fmaxf(y1[jj] + bo1, 0.f));
    __syncthreads();

    f32x4 y2[2] = { f32x4{0,0,0,0}, f32x4{0,0,0,0} };
#pragma unroll
    for (int kt = 0; kt < 4; ++kt) {
      bf16x8 a = *(const bf16x8*)&F2s[f2idx(lr, kt * 32 + lg * 8)];
#pragma unroll
      for (int ts = 0; ts < 2; ++ts) {
        bf16x8 b = *(const bf16x8*)(wsp + 344064 + ((wid + ts * 8) * 4 + kt) * 512 + lane * 8);
        y2[ts] = MFMA16(a, b, y2[ts]);
      }
    }
    float bo2[2] = { b_out2[wid * 16 + lr], b_out2[(wid + 8) * 16 + lr] };
#pragma unroll
    for (int ts = 0; ts < 2; ++ts)
#pragma unroll
      for (int jj = 0; jj < 4; ++jj)
        F1s[f1idx(lg * 4 + jj, (wid + ts * 8) * 16 + lr)] =
            f2bf(fmaxf(y2[ts][jj] + bo2[ts], 0.f));
    __syncthreads();

    if (wid < 2) {
      f32x4 y3 = {0, 0, 0, 0};
#pragma unroll
      for (int kt = 0; kt < 8; ++kt) {
        bf16x8 a = *(const bf16x8*)&F1s[f1idx(lr, kt * 32 + lg * 8)];
        bf16x8 b = *(const bf16x8*)(wsp + 376832 + (wid * 8 + kt) * 512 + lane * 8);
        y3 = MFMA16(a, b, y3);
      }
      float bo3 = b_out3[wid * 16 + lr];
#pragma unroll
      for (int jj = 0; jj < 4; ++jj)
        out[(size_t)(b0 + j * 16 + lg * 4 + jj) * 32 + wid * 16 + lr] = y3[jj] + bo3;
    }
  }
}

extern "C" void kernel_launch(void* const* d_in, const int* in_sizes, int n_in,
                              void* d_out, int out_size, void* d_ws, size_t ws_size,
                              hipStream_t stream) {
  (void)in_sizes; (void)n_in; (void)out_size; (void)ws_size;
  const float* seq    = (const float*)d_in[0];
  const float* h1     = (const float*)d_in[1];
  const float* c1     = (const float*)d_in[2];
  const float* h2     = (const float*)d_in[3];
  const float* c2     = (const float*)d_in[4];
  const float* W_in1  = (const float*)d_in[5];
  const float* b_in1  = (const float*)d_in[6];
  const float* W_in2  = (const float*)d_in[7];
  const float* b_in2  = (const float*)d_in[8];
  const float* W_in3  = (const float*)d_in[9];
  const float* b_in3  = (const float*)d_in[10];
  const float* Wih1   = (const float*)d_in[11];
  const float* Whh1   = (const float*)d_in[12];
  const float* bih1   = (const float*)d_in[13];
  const float* bhh1   = (const float*)d_in[14];
  const float* Wih2   = (const float*)d_in[15];
  const float* Whh2   = (const float*)d_in[16];
  const float* bih2   = (const float*)d_in[17];
  const float* bhh2   = (const float*)d_in[18];
  const float* W_out1 = (const float*)d_in[19];
  const float* b_out1 = (const float*)d_in[20];
  const float* W_out2 = (const float*)d_in[21];
  const float* b_out2 = (const float*)d_in[22];
  const float* W_out3 = (const float*)d_in[23];
  const float* b_out3 = (const float*)d_in[24];
  u16* ws = (u16*)d_ws;
  float* out = (float*)d_out;

  // zero exchange flags (ws is poisoned once before timing; flags are
  // value-encoded per call and MUST start at 0 every launch)
  hipMemsetAsync((char*)d_ws + FLH_OFF, 0, 4096, stream);

  hipLaunchKernelGGL(prep_kernel, dim3(512), dim3(256), 0, stream,
                     Wih1, Whh1, bih1, bhh1, Wih2, Whh2, bih2, bhh2,
                     W_in1, W_in2, W_in3, W_out1, W_out2, W_out3, ws);

  // cooperative launch: guarantees all 256 blocks (1/CU) co-resident,
  // required for the inter-block exchange spin-waits.
  void* args[] = { (void*)&seq, (void*)&h1, (void*)&c1, (void*)&h2, (void*)&c2,
                   (void*)&b_in1, (void*)&b_in2, (void*)&b_in3,
                   (void*)&b_out1, (void*)&b_out2, (void*)&b_out3,
                   (void*)&ws, (void*)&out };
  hipLaunchCooperativeKernel((void*)scan_kernel, dim3(256), dim3(512), args, 0, stream);
}

// Round 4
// 10169.987 us; speedup vs baseline: 5.5818x; 5.5818x over previous
//
#include <hip/hip_runtime.h>

// ---------------------------------------------------------------------------
// Fused MLP -> 2-layer LSTM scan (T=256) -> MLP head, MI355X gfx950.
// R4: m201-style deep-pipelined weight stream. 128 blocks x 512 thr, 32 batch
// rows each. Weights pre-packed into a cyclic 640KB image of 40 x 16KB chunks
// (one chunk per phase, 40 phases/step). 5-slot LDS ring, issue chunk p+4 in
// phase p, phase-end s_waitcnt vmcnt(6) (3 chunks / 48KB in flight, never 0).
// mfma_f32_16x16x32_bf16, f32 c-state in VGPRs, setprio around MFMA.
// ---------------------------------------------------------------------------

typedef unsigned short u16;
typedef short bf16x8 __attribute__((ext_vector_type(8)));
typedef float f32x4 __attribute__((ext_vector_type(4)));

#define MFMA16(a, b, c) __builtin_amdgcn_mfma_f32_16x16x32_bf16((a), (b), (c), 0, 0, 0)

#define GLOAD_LDS(gp, lp) __builtin_amdgcn_global_load_lds( \
    (const __attribute__((address_space(1))) unsigned int*)(const void*)(gp), \
    (__attribute__((address_space(3))) unsigned int*)(void*)(lp), 16, 0, 0)

#define WAITBAR(N) do { \
  asm volatile("s_waitcnt vmcnt(" #N ")" ::: "memory"); \
  __builtin_amdgcn_sched_barrier(0); \
  __builtin_amdgcn_s_barrier(); \
  __builtin_amdgcn_sched_barrier(0); \
} while (0)

#define WAITBAR_LG(N) do { \
  asm volatile("s_waitcnt vmcnt(" #N ") lgkmcnt(0)" ::: "memory"); \
  __builtin_amdgcn_sched_barrier(0); \
  __builtin_amdgcn_s_barrier(); \
  __builtin_amdgcn_sched_barrier(0); \
} while (0)

#define LGKM_BAR do { \
  asm volatile("s_waitcnt lgkmcnt(0)" ::: "memory"); \
  __builtin_amdgcn_sched_barrier(0); \
  __builtin_amdgcn_s_barrier(); \
  __builtin_amdgcn_sched_barrier(0); \
} while (0)

__device__ __forceinline__ u16 f2bf(float f) {
  union { float f; unsigned u; } v; v.f = f;
  return (u16)((v.u + 0x7FFFu + ((v.u >> 16) & 1u)) >> 16);  // RNE
}
__device__ __forceinline__ float fsig(float x) { return 1.0f / (1.0f + __expf(-x)); }
__device__ __forceinline__ float ftanh(float x) { return 2.0f / (1.0f + __expf(-2.0f * x)) - 1.0f; }

// ---- ws layout ------------------------------------------------------------
// u16 [0 .. 327680): cyclic image, 40 chunks x 8192 u16 (16KB). Granule g
// (16B) within chunk: g = (top*8 + wid)*64 + lane; elems e=0..7.
//   chunks 0..31 (cells): cc = cell*16 + kt*2 + hh; B elem =
//     cat(Wih,Whh)[(hh*2+top)*128 + wid*16 + (lane&15)][kt*32 + (lane>>4)*8 + e]
//   chunks 32,33 (W_in1, f=cc-32): W_in1[(top*8+wid)*16 + lr][f*32 + lg*8 + e]
//   chunks 34..37 (W_in2, f=cc-34): W_in2[wid*16+lr][(2f+top)*32 + lg*8 + e]
//   chunks 38,39 (W_in3, f=cc-38): W_in3[wid*16+lr][(2f+top)*32 + lg*8 + e]
// u16 327680: Wo1 [128][128] row-major; 344064: Wo2 [256][128];
// u16 376832: Wo3 [32][256]
// f32 idx 192512: bs1[512]=bih1+bhh1; f32 193024: bs2[512]

__global__ void prep_kernel(const float* __restrict__ Wih1, const float* __restrict__ Whh1,
                            const float* __restrict__ bih1, const float* __restrict__ bhh1,
                            const float* __restrict__ Wih2, const float* __restrict__ Whh2,
                            const float* __restrict__ bih2, const float* __restrict__ bhh2,
                            const float* __restrict__ W_in1, const float* __restrict__ W_in2,
                            const float* __restrict__ W_in3,
                            const float* __restrict__ W_out1, const float* __restrict__ W_out2,
                            const float* __restrict__ W_out3,
                            u16* __restrict__ ws) {
  const int N_total = 386048;
  int stride = gridDim.x * blockDim.x;
  for (int idx = blockIdx.x * blockDim.x + threadIdx.x; idx < N_total; idx += stride) {
    if (idx < 327680) {                      // streamed image
      int cc = idx >> 13;                    // chunk 0..39
      int gran = (idx & 8191) >> 3;          // 0..1023
      int e = idx & 7;
      int lane = gran & 63, sub = gran >> 6; // sub 0..15
      int lr = lane & 15, lg = lane >> 4;
      int wid = sub & 7, top = sub >> 3;
      float v;
      if (cc < 32) {
        int cell = cc >> 4, kt = (cc >> 1) & 7, hh = cc & 1;
        int row = (hh * 2 + top) * 128 + wid * 16 + lr;
        int k = kt * 32 + lg * 8 + e;
        const float* Wih = cell ? Wih2 : Wih1;
        const float* Whh = cell ? Whh2 : Whh1;
        v = (k < 128) ? Wih[row * 128 + k] : Whh[row * 128 + (k - 128)];
      } else if (cc < 34) {
        int f = cc - 32;
        int row = (top * 8 + wid) * 16 + lr;
        v = W_in1[row * 64 + f * 32 + lg * 8 + e];
      } else if (cc < 38) {
        int f = cc - 34;
        v = W_in2[(wid * 16 + lr) * 256 + (2 * f + top) * 32 + lg * 8 + e];
      } else {
        int f = cc - 38;
        v = W_in3[(wid * 16 + lr) * 128 + (2 * f + top) * 32 + lg * 8 + e];
      }
      ws[idx] = f2bf(v);
    } else if (idx < 344064) { ws[idx] = f2bf(W_out1[idx - 327680]);
    } else if (idx < 376832) { ws[idx] = f2bf(W_out2[idx - 344064]);
    } else if (idx < 385024) { ws[idx] = f2bf(W_out3[idx - 376832]);
    } else if (idx < 385536) {
      int i = idx - 385024;
      ((float*)ws)[192512 + i] = bih1[i] + bhh1[i];
    } else {
      int i = idx - 385536;
      ((float*)ws)[193024 + i] = bih2[i] + bhh2[i];
    }
  }
}

__global__ __launch_bounds__(512, 2)
void lstm_fused(const float* __restrict__ seq,
                const float* __restrict__ h1_in, const float* __restrict__ c1_in,
                const float* __restrict__ h2_in, const float* __restrict__ c2_in,
                const float* __restrict__ b_in1, const float* __restrict__ b_in2,
                const float* __restrict__ b_in3,
                const float* __restrict__ b_out1, const float* __restrict__ b_out2,
                const float* __restrict__ b_out3,
                const u16* __restrict__ ws, float* __restrict__ out) {
  // LDS 136KB: ring 80K, XB 16K, H1/H2 8K each, F1 16K, F2 8K. 1 block/CU.
  __shared__ u16 ring[5][8192];
  __shared__ u16 XB[2][4096];
  __shared__ u16 H1s[4096];
  __shared__ u16 H2s[4096];
  __shared__ u16 F1[8192];
  __shared__ u16 F2[4096];

  const int tid = threadIdx.x;
  const int wid = tid >> 6, lane = tid & 63;
  const int lr = lane & 15, lg = lane >> 4;
  const int b0 = blockIdx.x * 32;

  // ---- helpers ----
  auto issue_chunk = [&](int cpos, int slot) {
    const u16* src = ws + cpos * 8192 + wid * 1024 + lane * 8;
    u16* dst = &ring[slot][wid * 1024];
    GLOAD_LDS(src, dst);
    GLOAD_LDS(src + 512, dst + 512);
  };
  auto ring_frag = [&](int slot, int top) -> bf16x8 {
    return *(const bf16x8*)&ring[slot][((top * 8 + wid) * 64 + lane) * 8];
  };
  auto img_frag = [&](int cpos, int top) -> bf16x8 {   // prologue: direct global
    return *(const bf16x8*)(ws + cpos * 8192 + ((top * 8 + wid) * 64 + lane) * 8);
  };
  auto ldsA128 = [&](const u16* buf, int r, int kg) -> bf16x8 {  // K=128, kg=k/8
    return *(const bf16x8*)&buf[((r * 16 + kg) ^ (r & 7)) * 8];
  };
  auto ldsA256 = [&](const u16* buf, int r, int kg) -> bf16x8 {  // K=256
    return *(const bf16x8*)&buf[((r * 32 + kg) ^ (r & 7)) * 8];
  };
  auto cvt8 = [&](float4 x0, float4 x1) -> bf16x8 {
    bf16x8 av;
    av[0] = (short)f2bf(x0.x); av[1] = (short)f2bf(x0.y);
    av[2] = (short)f2bf(x0.z); av[3] = (short)f2bf(x0.w);
    av[4] = (short)f2bf(x1.x); av[5] = (short)f2bf(x1.y);
    av[6] = (short)f2bf(x1.z); av[7] = (short)f2bf(x1.w);
    return av;
  };

  // ---- biases ----
  const float* bsp = (const float*)ws;
  float bc1[4], bc2[4];
#pragma unroll
  for (int g = 0; g < 4; ++g) {
    bc1[g] = bsp[192512 + g * 128 + wid * 16 + lr];
    bc2[g] = bsp[193024 + g * 128 + wid * 16 + lr];
  }
  float bL1[2] = { b_in1[wid * 16 + lr], b_in1[128 + wid * 16 + lr] };
  float bL2 = b_in2[wid * 16 + lr];
  float bL3 = b_in3[wid * 16 + lr];

  // ---- c-state: lane owns rows 16rt+lg*4+j, col wid*16+lr ----
  float cs1[2][4], cs2[2][4];
#pragma unroll
  for (int rt = 0; rt < 2; ++rt)
#pragma unroll
    for (int j = 0; j < 4; ++j) {
      size_t off = (size_t)(b0 + 16 * rt + lg * 4 + j) * 128 + 16 * wid + lr;
      cs1[rt][j] = c1_in[off];
      cs2[rt][j] = c2_in[off];
    }

  // ---- H init (f32 -> bf16, swizzled) ----
  {
    int idx = tid * 8;
    int r = idx >> 7;
    int c8 = (idx & 127) >> 3;
    const float* p1 = h1_in + (size_t)(b0 + r) * 128 + c8 * 8;
    const float* p2 = h2_in + (size_t)(b0 + r) * 128 + c8 * 8;
    bf16x8 v1, v2;
#pragma unroll
    for (int j = 0; j < 8; ++j) { v1[j] = (short)f2bf(p1[j]); v2[j] = (short)f2bf(p2[j]); }
    int g = ((r * 16 + c8) ^ (r & 7)) * 8;
    *(bf16x8*)&H1s[g] = v1;
    *(bf16x8*)&H2s[g] = v2;
  }
  __syncthreads();

  // ================= prologue: fc(0) -> XB[0] (direct global B reads) ======
  {
    float4 sq0[8];
#pragma unroll
    for (int rt = 0; rt < 2; ++rt)
#pragma unroll
      for (int f = 0; f < 2; ++f) {
        const float* sp = seq + ((size_t)(b0 + 16 * rt + lr) * 256 + 0) * 64 + f * 32 + lg * 8;
        sq0[(rt * 2 + f) * 2] = *(const float4*)sp;
        sq0[(rt * 2 + f) * 2 + 1] = *(const float4*)(sp + 4);
      }
    // L1
    f32x4 aL[2][2] = {};
#pragma unroll
    for (int f = 0; f < 2; ++f) {
      bf16x8 a[2];
#pragma unroll
      for (int rt = 0; rt < 2; ++rt)
        a[rt] = cvt8(sq0[(rt * 2 + f) * 2], sq0[(rt * 2 + f) * 2 + 1]);
#pragma unroll
      for (int ts = 0; ts < 2; ++ts) {
        bf16x8 b = img_frag(32 + f, ts);
        aL[0][ts] = MFMA16(a[0], b, aL[0][ts]);
        aL[1][ts] = MFMA16(a[1], b, aL[1][ts]);
      }
    }
#pragma unroll
    for (int rt = 0; rt < 2; ++rt)
#pragma unroll
      for (int ts = 0; ts < 2; ++ts)
#pragma unroll
        for (int j = 0; j < 4; ++j) {
          int r = 16 * rt + lg * 4 + j, c = (ts * 8 + wid) * 16 + lr;
          F1[(r * 256 + c) ^ ((r & 7) << 3)] = f2bf(fmaxf(aL[rt][ts][j] + bL1[ts], 0.f));
        }
    __syncthreads();
    // L2
    f32x4 aM[2] = {};
#pragma unroll
    for (int f = 0; f < 4; ++f)
#pragma unroll
      for (int ktl = 0; ktl < 2; ++ktl) {
        int kg = (2 * f + ktl) * 4 + lg;
        bf16x8 b = img_frag(34 + f, ktl);
        aM[0] = MFMA16(ldsA256(F1, lr, kg), b, aM[0]);
        aM[1] = MFMA16(ldsA256(F1, 16 + lr, kg), b, aM[1]);
      }
#pragma unroll
    for (int rt = 0; rt < 2; ++rt)
#pragma unroll
      for (int j = 0; j < 4; ++j) {
        int r = 16 * rt + lg * 4 + j, c = wid * 16 + lr;
        F2[(r * 128 + c) ^ ((r & 7) << 3)] = f2bf(fmaxf(aM[rt][j] + bL2, 0.f));
      }
    __syncthreads();
    // L3
    f32x4 aN[2] = {};
#pragma unroll
    for (int f = 0; f < 2; ++f)
#pragma unroll
      for (int ktl = 0; ktl < 2; ++ktl) {
        int kg = (2 * f + ktl) * 4 + lg;
        bf16x8 b = img_frag(38 + f, ktl);
        aN[0] = MFMA16(ldsA128(F2, lr, kg), b, aN[0]);
        aN[1] = MFMA16(ldsA128(F2, 16 + lr, kg), b, aN[1]);
      }
#pragma unroll
    for (int rt = 0; rt < 2; ++rt)
#pragma unroll
      for (int j = 0; j < 4; ++j) {
        int r = 16 * rt + lg * 4 + j, c = wid * 16 + lr;
        XB[0][(r * 128 + c) ^ ((r & 7) << 3)] = f2bf(fmaxf(aN[rt][j] + bL3, 0.f));
      }
    __syncthreads();
  }

  // ---- ring prologue: chunks 0..3 in flight, chunk 0 certified ----
  issue_chunk(0, 0);
  issue_chunk(1, 1);
  issue_chunk(2, 2);
  issue_chunk(3, 3);
  WAITBAR(6);

  float4 sq[8];   // seq prefetch for t+1

  // ================= scan =================
  for (int t = 0; t < 256; ++t) {
    // ---- cell1: phases 0..15 ----
    f32x4 acc1[2][4] = {};
    {
      bf16x8 aA[2];
#pragma unroll
      for (int p = 0; p < 16; ++p) {
        const int kt = p >> 1, hh = p & 1;
        issue_chunk((p + 4) % 40, (p + 4) % 5);
        if (hh == 0) {
          const u16* ab = (kt < 4) ? &XB[t & 1][0] : H1s;
          int kg = (kt & 3) * 4 + lg;
          aA[0] = ldsA128(ab, lr, kg);
          aA[1] = ldsA128(ab, 16 + lr, kg);
        }
        __builtin_amdgcn_s_setprio(1);
#pragma unroll
        for (int g2 = 0; g2 < 2; ++g2) {
          bf16x8 b = ring_frag(p % 5, g2);
          acc1[0][hh * 2 + g2] = MFMA16(aA[0], b, acc1[0][hh * 2 + g2]);
          acc1[1][hh * 2 + g2] = MFMA16(aA[1], b, acc1[1][hh * 2 + g2]);
        }
        __builtin_amdgcn_s_setprio(0);
        WAITBAR(6);
      }
    }
    // ---- ew1 -> H1 ----
#pragma unroll
    for (int rt = 0; rt < 2; ++rt)
#pragma unroll
      for (int j = 0; j < 4; ++j) {
        float gi = acc1[rt][0][j] + bc1[0];
        float gf = acc1[rt][1][j] + bc1[1];
        float gg = acc1[rt][2][j] + bc1[2];
        float go = acc1[rt][3][j] + bc1[3];
        float cn = fsig(gf) * cs1[rt][j] + fsig(gi) * ftanh(gg);
        cs1[rt][j] = cn;
        int r = 16 * rt + lg * 4 + j;
        H1s[(r * 128 + wid * 16 + lr) ^ ((r & 7) << 3)] = f2bf(fsig(go) * ftanh(cn));
      }
    LGKM_BAR;

    // ---- cell2: phases 16..31 ----
    f32x4 acc2[2][4] = {};
    {
      bf16x8 aA[2];
#pragma unroll
      for (int p = 16; p < 32; ++p) {
        const int kt = (p - 16) >> 1, hh = (p - 16) & 1;
        issue_chunk((p + 4) % 40, (p + 4) % 5);
        if (p == 28) {   // seq prefetch for t+1 (8 loads -> vmcnt +8)
          int t1 = (t < 255) ? t + 1 : 255;
#pragma unroll
          for (int rt = 0; rt < 2; ++rt)
#pragma unroll
            for (int f = 0; f < 2; ++f) {
              const float* sp = seq + ((size_t)(b0 + 16 * rt + lr) * 256 + t1) * 64 + f * 32 + lg * 8;
              sq[(rt * 2 + f) * 2] = *(const float4*)sp;
              sq[(rt * 2 + f) * 2 + 1] = *(const float4*)(sp + 4);
            }
        }
        if (hh == 0) {
          const u16* ab = (kt < 4) ? H1s : H2s;
          int kg = (kt & 3) * 4 + lg;
          aA[0] = ldsA128(ab, lr, kg);
          aA[1] = ldsA128(ab, 16 + lr, kg);
        }
        __builtin_amdgcn_s_setprio(1);
#pragma unroll
        for (int g2 = 0; g2 < 2; ++g2) {
          bf16x8 b = ring_frag(p % 5, g2);
          acc2[0][hh * 2 + g2] = MFMA16(aA[0], b, acc2[0][hh * 2 + g2]);
          acc2[1][hh * 2 + g2] = MFMA16(aA[1], b, acc2[1][hh * 2 + g2]);
        }
        __builtin_amdgcn_s_setprio(0);
        if (p == 28 || p == 29 || p == 30) { WAITBAR(14); } else { WAITBAR(6); }
      }
    }
    // ---- ew2 -> H2 ----
#pragma unroll
    for (int rt = 0; rt < 2; ++rt)
#pragma unroll
      for (int j = 0; j < 4; ++j) {
        float gi = acc2[rt][0][j] + bc2[0];
        float gf = acc2[rt][1][j] + bc2[1];
        float gg = acc2[rt][2][j] + bc2[2];
        float go = acc2[rt][3][j] + bc2[3];
        float cn = fsig(gf) * cs2[rt][j] + fsig(gi) * ftanh(gg);
        cs2[rt][j] = cn;
        int r = 16 * rt + lg * 4 + j;
        H2s[(r * 128 + wid * 16 + lr) ^ ((r & 7) << 3)] = f2bf(fsig(go) * ftanh(cn));
      }
    LGKM_BAR;

    // ---- fc(t+1): phases 32..39 ----
    {
      // L1: phases 32,33
      f32x4 aL[2][2] = {};
#pragma unroll
      for (int f = 0; f < 2; ++f) {
        const int p = 32 + f;
        issue_chunk((p + 4) % 40, (p + 4) % 5);
        bf16x8 a[2];
#pragma unroll
        for (int rt = 0; rt < 2; ++rt)
          a[rt] = cvt8(sq[(rt * 2 + f) * 2], sq[(rt * 2 + f) * 2 + 1]);
        __builtin_amdgcn_s_setprio(1);
#pragma unroll
        for (int ts = 0; ts < 2; ++ts) {
          bf16x8 b = ring_frag(p % 5, ts);
          aL[0][ts] = MFMA16(a[0], b, aL[0][ts]);
          aL[1][ts] = MFMA16(a[1], b, aL[1][ts]);
        }
        __builtin_amdgcn_s_setprio(0);
        if (f == 0) { WAITBAR(6); }
        else {
#pragma unroll
          for (int rt = 0; rt < 2; ++rt)
#pragma unroll
            for (int ts = 0; ts < 2; ++ts)
#pragma unroll
              for (int j = 0; j < 4; ++j) {
                int r = 16 * rt + lg * 4 + j, c = (ts * 8 + wid) * 16 + lr;
                F1[(r * 256 + c) ^ ((r & 7) << 3)] = f2bf(fmaxf(aL[rt][ts][j] + bL1[ts], 0.f));
              }
          WAITBAR_LG(6);
        }
      }
      // L2: phases 34..37
      f32x4 aM[2] = {};
#pragma unroll
      for (int f = 0; f < 4; ++f) {
        const int p = 34 + f;
        issue_chunk((p + 4) % 40, (p + 4) % 5);
        bf16x8 a[2][2];
#pragma unroll
        for (int ktl = 0; ktl < 2; ++ktl) {
          int kg = (2 * f + ktl) * 4 + lg;
          a[0][ktl] = ldsA256(F1, lr, kg);
          a[1][ktl] = ldsA256(F1, 16 + lr, kg);
        }
        __builtin_amdgcn_s_setprio(1);
#pragma unroll
        for (int ktl = 0; ktl < 2; ++ktl) {
          bf16x8 b = ring_frag(p % 5, ktl);
          aM[0] = MFMA16(a[0][ktl], b, aM[0]);
          aM[1] = MFMA16(a[1][ktl], b, aM[1]);
        }
        __builtin_amdgcn_s_setprio(0);
        if (f < 3) { WAITBAR(6); }
        else {
#pragma unroll
          for (int rt = 0; rt < 2; ++rt)
#pragma unroll
            for (int j = 0; j < 4; ++j) {
              int r = 16 * rt + lg * 4 + j, c = wid * 16 + lr;
              F2[(r * 128 + c) ^ ((r & 7) << 3)] = f2bf(fmaxf(aM[rt][j] + bL2, 0.f));
            }
          WAITBAR_LG(6);
        }
      }
      // L3: phases 38,39 -> XB[(t+1)&1]
      f32x4 aN[2] = {};
#pragma unroll
      for (int f = 0; f < 2; ++f) {
        const int p = 38 + f;
        issue_chunk((p + 4) % 40, (p + 4) % 5);
        bf16x8 a[2][2];
#pragma unroll
        for (int ktl = 0; ktl < 2; ++ktl) {
          int kg = (2 * f + ktl) * 4 + lg;
          a[0][ktl] = ldsA128(F2, lr, kg);
          a[1][ktl] = ldsA128(F2, 16 + lr, kg);
        }
        __builtin_amdgcn_s_setprio(1);
#pragma unroll
        for (int ktl = 0; ktl < 2; ++ktl) {
          bf16x8 b = ring_frag(p % 5, ktl);
          aN[0] = MFMA16(a[0][ktl], b, aN[0]);
          aN[1] = MFMA16(a[1][ktl], b, aN[1]);
        }
        __builtin_amdgcn_s_setprio(0);
        if (f == 0) { WAITBAR(6); }
        else {
          u16* xb = &XB[(t + 1) & 1][0];
#pragma unroll
          for (int rt = 0; rt < 2; ++rt)
#pragma unroll
            for (int j = 0; j < 4; ++j) {
              int r = 16 * rt + lg * 4 + j, c = wid * 16 + lr;
              xb[(r * 128 + c) ^ ((r & 7) << 3)] = f2bf(fmaxf(aN[rt][j] + bL3, 0.f));
            }
          WAITBAR_LG(6);
        }
      }
    }
  }

  // ---- drain, then head ----
  asm volatile("s_waitcnt vmcnt(0)" ::: "memory");
  __syncthreads();

  const u16* Wo1 = ws + 327680;
  const u16* Wo2 = ws + 344064;
  const u16* Wo3 = ws + 376832;
  { // Y1 = relu(h2 @ Wo1^T + b_out1) -> F2
    f32x4 acc[2] = {};
#pragma unroll
    for (int kt = 0; kt < 4; ++kt) {
      bf16x8 a[2];
#pragma unroll
      for (int rt = 0; rt < 2; ++rt) {
        int r = 16 * rt + lr;
        a[rt] = *(const bf16x8*)&H2s[((r * 16 + kt * 4 + lg) ^ (r & 7)) * 8];
      }
      bf16x8 b = *(const bf16x8*)(Wo1 + (size_t)(16 * wid + lr) * 128 + kt * 32 + lg * 8);
      acc[0] = MFMA16(a[0], b, acc[0]);
      acc[1] = MFMA16(a[1], b, acc[1]);
    }
    float bo1v = b_out1[16 * wid + lr];
#pragma unroll
    for (int rt = 0; rt < 2; ++rt)
#pragma unroll
      for (int j = 0; j < 4; ++j) {
        int r = 16 * rt + lg * 4 + j, c = 16 * wid + lr;
        F2[(r * 128 + c) ^ ((r & 7) << 3)] = f2bf(fmaxf(acc[rt][j] + bo1v, 0.f));
      }
    __syncthreads();
  }
  { // Y2 = relu(Y1 @ Wo2^T + b_out2) -> F1
    f32x4 acc[2][2] = {};
#pragma unroll
    for (int kt = 0; kt < 4; ++kt) {
      bf16x8 a[2];
#pragma unroll
      for (int rt = 0; rt < 2; ++rt) {
        int r = 16 * rt + lr;
        a[rt] = *(const bf16x8*)&F2[((r * 16 + kt * 4 + lg) ^ (r & 7)) * 8];
      }
#pragma unroll
      for (int ci = 0; ci < 2; ++ci) {
        bf16x8 b = *(const bf16x8*)(Wo2 + (size_t)(32 * wid + 16 * ci + lr) * 128 + kt * 32 + lg * 8);
        acc[0][ci] = MFMA16(a[0], b, acc[0][ci]);
        acc[1][ci] = MFMA16(a[1], b, acc[1][ci]);
      }
    }
#pragma unroll
    for (int rt = 0; rt < 2; ++rt)
#pragma unroll
      for (int ci = 0; ci < 2; ++ci)
#pragma unroll
        for (int j = 0; j < 4; ++j) {
          int r = 16 * rt + lg * 4 + j, c = 32 * wid + 16 * ci + lr;
          float v = fmaxf(acc[rt][ci][j] + b_out2[c], 0.f);
          F1[(r * 256 + c) ^ ((r & 7) << 3)] = f2bf(v);
        }
    __syncthreads();
  }
  if (wid < 4) { // Y3 = Y2 @ Wo3^T + b_out3
    int rt = wid >> 1, ci = wid & 1;
    f32x4 acc = {};
#pragma unroll
    for (int kt = 0; kt < 8; ++kt) {
      int r = 16 * rt + lr;
      bf16x8 a = *(const bf16x8*)&F1[((r * 32 + kt * 4 + lg) ^ (r & 7)) * 8];
      bf16x8 b = *(const bf16x8*)(Wo3 + (size_t)(16 * ci + lr) * 256 + kt * 32 + lg * 8);
      acc = MFMA16(a, b, acc);
    }
    float bo3v = b_out3[16 * ci + lr];
#pragma unroll
    for (int j = 0; j < 4; ++j)
      out[(size_t)(b0 + 16 * rt + lg * 4 + j) * 32 + 16 * ci + lr] = acc[j] + bo3v;
  }
}

extern "C" void kernel_launch(void* const* d_in, const int* in_sizes, int n_in,
                              void* d_out, int out_size, void* d_ws, size_t ws_size,
                              hipStream_t stream) {
  (void)in_sizes; (void)n_in; (void)out_size; (void)ws_size;
  const float* seq    = (const float*)d_in[0];
  const float* h1     = (const float*)d_in[1];
  const float* c1     = (const float*)d_in[2];
  const float* h2     = (const float*)d_in[3];
  const float* c2     = (const float*)d_in[4];
  const float* W_in1  = (const float*)d_in[5];
  const float* b_in1  = (const float*)d_in[6];
  const float* W_in2  = (const float*)d_in[7];
  const float* b_in2  = (const float*)d_in[8];
  const float* W_in3  = (const float*)d_in[9];
  const float* b_in3  = (const float*)d_in[10];
  const float* Wih1   = (const float*)d_in[11];
  const float* Whh1   = (const float*)d_in[12];
  const float* bih1   = (const float*)d_in[13];
  const float* bhh1   = (const float*)d_in[14];
  const float* Wih2   = (const float*)d_in[15];
  const float* Whh2   = (const float*)d_in[16];
  const float* bih2   = (const float*)d_in[17];
  const float* bhh2   = (const float*)d_in[18];
  const float* W_out1 = (const float*)d_in[19];
  const float* b_out1 = (const float*)d_in[20];
  const float* W_out2 = (const float*)d_in[21];
  const float* b_out2 = (const float*)d_in[22];
  const float* W_out3 = (const float*)d_in[23];
  const float* b_out3 = (const float*)d_in[24];
  u16* ws = (u16*)d_ws;
  float* out = (float*)d_out;

  hipLaunchKernelGGL(prep_kernel, dim3(512), dim3(256), 0, stream,
                     Wih1, Whh1, bih1, bhh1, Wih2, Whh2, bih2, bhh2,
                     W_in1, W_in2, W_in3, W_out1, W_out2, W_out3, ws);
  hipLaunchKernelGGL(lstm_fused, dim3(128), dim3(512), 0, stream,
                     seq, h1, c1, h2, c2, b_in1, b_in2, b_in3,
                     b_out1, b_out2, b_out3, ws, out);
}

// Round 5
// 1641.939 us; speedup vs baseline: 34.5733x; 6.1939x over previous
//
#include <hip/hip_runtime.h>

// ---------------------------------------------------------------------------
// R5: resident-weight LSTM scan, decoupled fc_in.
//  - fc_chunk: batched GEMM computes x = fc_in(seq) for a 32-step t-chunk
//    into ws XBUF (bf16).  2048 blocks x 256 thr, 64 rows (2 batches) each.
//  - scan_chunk: 256 blocks x 512 thr, 16 batch rows each. Cell weights:
//    wgt1[4][8] + wgt2v[4][4] in VGPRs (192/wave), cell2 h2-half in LDS
//    (128 KB). Wave owns ALL 4 gates for 16 h-cols -> elementwise fully
//    in-register (no gate buffer). 4 lgkm-barriers/step; per-step global
//    traffic = 4 KB x-prefetch only. Head fused into last chunk.
//  ws requirement: ~42 MB (XBUF 32 MB @ byte 8388608).
// ---------------------------------------------------------------------------

typedef unsigned short u16;
typedef short bf16x8 __attribute__((ext_vector_type(8)));
typedef float f32x4 __attribute__((ext_vector_type(4)));
typedef unsigned short u16x4 __attribute__((ext_vector_type(4)));

#define MFMA16(a, b, c) __builtin_amdgcn_mfma_f32_16x16x32_bf16((a), (b), (c), 0, 0, 0)

#define GLOAD_LDS(gp, lp) __builtin_amdgcn_global_load_lds( \
    (const __attribute__((address_space(1))) unsigned int*)(const void*)(gp), \
    (__attribute__((address_space(3))) unsigned int*)(void*)(lp), 16, 0, 0)

// raw barrier with lgkm-only drain (keeps x-prefetch vmem in flight)
#define LGKM_BAR do { \
  asm volatile("s_waitcnt lgkmcnt(0)" ::: "memory"); \
  __builtin_amdgcn_sched_barrier(0); \
  __builtin_amdgcn_s_barrier(); \
  __builtin_amdgcn_sched_barrier(0); \
} while (0)

__device__ __forceinline__ u16 f2bf(float f) {
  union { float f; unsigned u; } v; v.f = f;
  return (u16)((v.u + 0x7FFFu + ((v.u >> 16) & 1u)) >> 16);  // RNE
}
__device__ __forceinline__ float fsig(float x) { return 1.0f / (1.0f + __expf(-x)); }
__device__ __forceinline__ float ftanh(float x) { return 2.0f / (1.0f + __expf(-2.0f * x)) - 1.0f; }

// ---- ws layout (u16 / f32 indices; byte offsets in comments) -------------
#define WC1_U   0         // 256 frags: ((w*4+g)*8+kf)*512 ; Wcat1[g*128+w*16+lr][kf*32+lg*8+e]
#define WC2V_U  131072    // 128 frags: ((w*4+g)*4+kf)*512 ; Wih2 (k<128)
#define WC2L_U  196608    // 128 frags: ((w*4+g)*4+kf)*512 ; Whh2
#define W1_U    262144    // 32 frags (n*2+kf): W_in1[n*16+lr][kf*32+lg*8+e]
#define W2_U    278528    // 64 frags (n*8+kf): W_in2
#define W3_U    311296    // 32 frags (n*4+kf): W_in3
#define WO1_U   327680    // 32 frags (n*4+kf): W_out1
#define WO2_U   344064    // 64 frags (n*4+kf): W_out2
#define WO3_U   376832    // 16 frags (n*8+kf): W_out3
#define BS1_F   192512    // f32[512] = bih1+bhh1   (byte 770048)
#define BS2_F   193024    // f32[512] = bih2+bhh2
#define STH1_U  393216    // bf16[4096*128] h1 state (byte 786432)
#define STH2_U  917504    // bf16[4096*128] h2 state
#define C1_F    720896    // f32[4096*128] c1 state (byte 2883584)
#define C2_F    1245184   // f32[4096*128] c2 state
#define XB_U    4194304   // bf16[32][4096][128] x chunk buffer (byte 8388608)
#define TC      32        // t-chunk
#define NCH     8         // chunks

// ======================= prep ==============================================
__global__ void prep_kernel(const float* __restrict__ Wih1, const float* __restrict__ Whh1,
                            const float* __restrict__ bih1, const float* __restrict__ bhh1,
                            const float* __restrict__ Wih2, const float* __restrict__ Whh2,
                            const float* __restrict__ bih2, const float* __restrict__ bhh2,
                            const float* __restrict__ W_in1, const float* __restrict__ W_in2,
                            const float* __restrict__ W_in3,
                            const float* __restrict__ W_out1, const float* __restrict__ W_out2,
                            const float* __restrict__ W_out3,
                            const float* __restrict__ h1_in, const float* __restrict__ h2_in,
                            const float* __restrict__ c1_in, const float* __restrict__ c2_in,
                            u16* __restrict__ wsu) {
  float* wsf = (float*)wsu;
  const int N_total = 2490368;
  int stride = gridDim.x * blockDim.x;
  for (int idx = blockIdx.x * blockDim.x + threadIdx.x; idx < N_total; idx += stride) {
    if (idx < 385024) {                       // weight frag images
      int within = idx & 511;
      int frag = (idx >> 9);                  // global frag idx (u16 base idx>>9)
      int lane = within >> 3, e = within & 7;
      int lr = lane & 15, lg = lane >> 4;
      int k8 = lg * 8 + e;                    // k within 32-slice
      float v;
      if (idx < 131072) {                     // WC1: frag = (w*4+g)*8+kf
        int kf = frag & 7, g = (frag >> 3) & 3, w = frag >> 5;
        int row = g * 128 + w * 16 + lr;
        int k = kf * 32 + k8;
        v = (k < 128) ? Wih1[row * 128 + k] : Whh1[row * 128 + (k - 128)];
      } else if (idx < 196608) {              // WC2V: Wih2
        int f = frag - 256;                   // frag idx rel
        int kf = f & 3, g = (f >> 2) & 3, w = f >> 4;
        v = Wih2[(g * 128 + w * 16 + lr) * 128 + kf * 32 + k8];
      } else if (idx < 262144) {              // WC2L: Whh2
        int f = frag - 384;
        int kf = f & 3, g = (f >> 2) & 3, w = f >> 4;
        v = Whh2[(g * 128 + w * 16 + lr) * 128 + kf * 32 + k8];
      } else if (idx < 278528) {              // W1
        int f = frag - 512; int kf = f & 1, n = f >> 1;
        v = W_in1[(n * 16 + lr) * 64 + kf * 32 + k8];
      } else if (idx < 311296) {              // W2
        int f = frag - 544; int kf = f & 7, n = f >> 3;
        v = W_in2[(n * 16 + lr) * 256 + kf * 32 + k8];
      } else if (idx < 327680) {              // W3
        int f = frag - 608; int kf = f & 3, n = f >> 2;
        v = W_in3[(n * 16 + lr) * 128 + kf * 32 + k8];
      } else if (idx < 344064) {              // WO1
        int f = frag - 640; int kf = f & 3, n = f >> 2;
        v = W_out1[(n * 16 + lr) * 128 + kf * 32 + k8];
      } else if (idx < 376832) {              // WO2
        int f = frag - 672; int kf = f & 3, n = f >> 2;
        v = W_out2[(n * 16 + lr) * 128 + kf * 32 + k8];
      } else {                                // WO3
        int f = frag - 736; int kf = f & 7, n = f >> 3;
        v = W_out3[(n * 16 + lr) * 256 + kf * 32 + k8];
      }
      wsu[idx] = f2bf(v);
    } else if (idx < 385536) {
      int i = idx - 385024; wsf[BS1_F + i] = bih1[i] + bhh1[i];
    } else if (idx < 386048) {
      int i = idx - 385536; wsf[BS2_F + i] = bih2[i] + bhh2[i];
    } else if (idx < 393216) {
      // pad gap: nothing
    } else if (idx < 917504) {
      int i = idx - 393216; wsu[STH1_U + i] = f2bf(h1_in[i]);
    } else if (idx < 1441792) {
      int i = idx - 917504; wsu[STH2_U + i] = f2bf(h2_in[i]);
    } else if (idx < 1966080) {
      int i = idx - 1441792; wsf[C1_F + i] = c1_in[i];
    } else {
      int i = idx - 1966080; wsf[C2_F + i] = c2_in[i];
    }
  }
}

// ======================= fc_in chunk (x = relu-MLP(seq)) ===================
// 2048 blocks x 256 thr; block handles 2 batches x 32 t = 64 rows.
__global__ __launch_bounds__(256, 2)
void fc_chunk(const float* __restrict__ seq,
              const float* __restrict__ b_in1, const float* __restrict__ b_in2,
              const float* __restrict__ b_in3,
              u16* __restrict__ wsu, int t0) {
  __shared__ u16 SEQs[4096];   // [64][64]
  __shared__ u16 F1s[16384];   // [64][256]
  __shared__ u16 F2s[8192];    // [64][128]
  const int tid = threadIdx.x;
  const int wid = tid >> 6, lane = tid & 63;
  const int lr = lane & 15, lg = lane >> 4;
  const int bid = blockIdx.x;

  // stage seq rows (rho = db*32 + tl), f32 -> bf16 swizzled
#pragma unroll
  for (int i = 0; i < 4; ++i) {
    int f = i * 1024 + tid * 4;
    int rho = f >> 6, k = f & 63;
    int b = bid * 2 + (rho >> 5), tl = rho & 31;
    float4 v = *(const float4*)(seq + ((size_t)b * 256 + t0 + tl) * 64 + k);
    u16x4 o = { f2bf(v.x), f2bf(v.y), f2bf(v.z), f2bf(v.w) };
    *(u16x4*)&SEQs[(rho * 64 + k) ^ ((rho & 7) << 3)] = o;
  }
  __syncthreads();

  // ---- L1: [64,256] = relu(SEQ @ W1^T + b1), K=64; wave n-tiles 4w..4w+3 --
  {
    f32x4 a1[4][4] = {};
#pragma unroll
    for (int kf = 0; kf < 2; ++kf) {
      bf16x8 A[4];
#pragma unroll
      for (int rt = 0; rt < 4; ++rt) {
        int r = 16 * rt + lr;
        A[rt] = *(const bf16x8*)&SEQs[(r * 64 + (kf * 4 + lg) * 8) ^ ((r & 7) << 3)];
      }
#pragma unroll
      for (int n = 0; n < 4; ++n) {
        bf16x8 B = *(const bf16x8*)(wsu + W1_U + (size_t)(((4 * wid + n) * 2 + kf) * 512) + lane * 8);
#pragma unroll
        for (int rt = 0; rt < 4; ++rt) a1[rt][n] = MFMA16(A[rt], B, a1[rt][n]);
      }
    }
#pragma unroll
    for (int n = 0; n < 4; ++n) {
      float bb = b_in1[(4 * wid + n) * 16 + lr];
#pragma unroll
      for (int rt = 0; rt < 4; ++rt)
#pragma unroll
        for (int j = 0; j < 4; ++j) {
          int r = 16 * rt + lg * 4 + j, c = (4 * wid + n) * 16 + lr;
          F1s[(r * 256 + c) ^ ((r & 7) << 3)] = f2bf(fmaxf(a1[rt][n][j] + bb, 0.f));
        }
    }
  }
  __syncthreads();

  // ---- L2: [64,128], K=256; wave n-tiles 2w, 2w+1 ----
  {
    f32x4 a2[4][2] = {};
#pragma unroll
    for (int kf = 0; kf < 8; ++kf) {
      bf16x8 A[4];
#pragma unroll
      for (int rt = 0; rt < 4; ++rt) {
        int r = 16 * rt + lr;
        A[rt] = *(const bf16x8*)&F1s[(r * 256 + (kf * 4 + lg) * 8) ^ ((r & 7) << 3)];
      }
#pragma unroll
      for (int n = 0; n < 2; ++n) {
        bf16x8 B = *(const bf16x8*)(wsu + W2_U + (size_t)(((2 * wid + n) * 8 + kf) * 512) + lane * 8);
#pragma unroll
        for (int rt = 0; rt < 4; ++rt) a2[rt][n] = MFMA16(A[rt], B, a2[rt][n]);
      }
    }
#pragma unroll
    for (int n = 0; n < 2; ++n) {
      float bb = b_in2[(2 * wid + n) * 16 + lr];
#pragma unroll
      for (int rt = 0; rt < 4; ++rt)
#pragma unroll
        for (int j = 0; j < 4; ++j) {
          int r = 16 * rt + lg * 4 + j, c = (2 * wid + n) * 16 + lr;
          F2s[(r * 128 + c) ^ ((r & 7) << 3)] = f2bf(fmaxf(a2[rt][n][j] + bb, 0.f));
        }
    }
  }
  __syncthreads();

  // ---- L3: [64,128], K=128 -> XBUF global ----
  {
    f32x4 a3[4][2] = {};
#pragma unroll
    for (int kf = 0; kf < 4; ++kf) {
      bf16x8 A[4];
#pragma unroll
      for (int rt = 0; rt < 4; ++rt) {
        int r = 16 * rt + lr;
        A[rt] = *(const bf16x8*)&F2s[(r * 128 + (kf * 4 + lg) * 8) ^ ((r & 7) << 3)];
      }
#pragma unroll
      for (int n = 0; n < 2; ++n) {
        bf16x8 B = *(const bf16x8*)(wsu + W3_U + (size_t)(((2 * wid + n) * 4 + kf) * 512) + lane * 8);
#pragma unroll
        for (int rt = 0; rt < 4; ++rt) a3[rt][n] = MFMA16(A[rt], B, a3[rt][n]);
      }
    }
#pragma unroll
    for (int n = 0; n < 2; ++n) {
      float bb = b_in3[(2 * wid + n) * 16 + lr];
#pragma unroll
      for (int rt = 0; rt < 4; ++rt)
#pragma unroll
        for (int j = 0; j < 4; ++j) {
          int rho = 16 * rt + lg * 4 + j;
          int b = bid * 2 + (rho >> 5), tl = rho & 31;
          int c = (2 * wid + n) * 16 + lr;
          wsu[XB_U + ((size_t)tl * 4096 + b) * 128 + c] = f2bf(fmaxf(a3[rt][n][j] + bb, 0.f));
        }
    }
  }
}

// ======================= scan chunk ========================================
// 256 blocks x 512 thr; block owns 16 batch rows; 32 steps.
__global__ __launch_bounds__(512, 2)
void scan_chunk(u16* __restrict__ wsu, float* __restrict__ out,
                const float* __restrict__ b_out1, const float* __restrict__ b_out2,
                const float* __restrict__ b_out3, int last) {
  __shared__ u16 Wl[65536];                  // 128 KB: cell2 h2-half B-frags
  __shared__ u16 XBs[2048], H1s[2048], H2s[2048];   // [16][128] each

  float* wsf = (float*)wsu;
  const int tid = threadIdx.x;
  const int wid = tid >> 6, lane = tid & 63;
  const int lr = lane & 15, lg = lane >> 4;
  const int b0 = blockIdx.x * 16;
  const int r5 = tid >> 5, c5 = (tid & 31) * 4;

  // ---- register-resident weights ----
  bf16x8 wgt1[4][8], wgt2v[4][4];
#pragma unroll
  for (int g = 0; g < 4; ++g) {
#pragma unroll
    for (int kf = 0; kf < 8; ++kf)
      wgt1[g][kf] = *(const bf16x8*)(wsu + WC1_U + (size_t)(((wid * 4 + g) * 8 + kf) * 512) + lane * 8);
#pragma unroll
    for (int kf = 0; kf < 4; ++kf)
      wgt2v[g][kf] = *(const bf16x8*)(wsu + WC2V_U + (size_t)(((wid * 4 + g) * 4 + kf) * 512) + lane * 8);
  }
  // ---- copy WC2L -> Wl LDS (frag-linear) ----
#pragma unroll
  for (int i = 0; i < 16; ++i)
    GLOAD_LDS(wsu + WC2L_U + wid * 8192 + i * 512 + lane * 8, &Wl[wid * 8192 + i * 512]);

  // ---- state: h tiles + c regs + biases + x(0) ----
  u16x4 hh1 = *(const u16x4*)(wsu + STH1_U + (size_t)(b0 + r5) * 128 + c5);
  u16x4 hh2 = *(const u16x4*)(wsu + STH2_U + (size_t)(b0 + r5) * 128 + c5);
  u16x4 xq  = *(const u16x4*)(wsu + XB_U + ((size_t)0 * 4096 + b0 + r5) * 128 + c5);
  float cs1[4], cs2[4], bc1[4], bc2[4];
#pragma unroll
  for (int j = 0; j < 4; ++j) {
    cs1[j] = wsf[C1_F + (size_t)(b0 + lg * 4 + j) * 128 + 16 * wid + lr];
    cs2[j] = wsf[C2_F + (size_t)(b0 + lg * 4 + j) * 128 + 16 * wid + lr];
  }
#pragma unroll
  for (int g = 0; g < 4; ++g) {
    bc1[g] = wsf[BS1_F + g * 128 + 16 * wid + lr];
    bc2[g] = wsf[BS2_F + g * 128 + 16 * wid + lr];
  }
  {
    int sw = (r5 * 128 + c5) ^ ((r5 & 7) << 3);
    *(u16x4*)&H1s[sw] = hh1;
    *(u16x4*)&H2s[sw] = hh2;
    *(u16x4*)&XBs[sw] = xq;
  }
  __syncthreads();   // prologue full sync (also drains Wl gload_lds)

  // ================= 32-step scan =================
#pragma unroll 1
  for (int tl = 0; tl < TC; ++tl) {
    const bool ld = (tl < TC - 1);
    u16x4 xn;
    if (ld) xn = *(const u16x4*)(wsu + XB_U + ((size_t)(tl + 1) * 4096 + b0 + r5) * 128 + c5);

    // ---- cell1: A = [x | h1], weights fully in VGPRs ----
    f32x4 acc[4] = {};
#pragma unroll
    for (int kf = 0; kf < 8; ++kf) {
      const u16* ab = (kf < 4) ? XBs : H1s;
      int kg = (kf & 3) * 4 + lg;
      bf16x8 A = *(const bf16x8*)&ab[(lr * 128 + kg * 8) ^ ((lr & 7) << 3)];
#pragma unroll
      for (int g = 0; g < 4; ++g) acc[g] = MFMA16(A, wgt1[g][kf], acc[g]);
    }
    u16 hv[4];
#pragma unroll
    for (int j = 0; j < 4; ++j) {
      float gi = acc[0][j] + bc1[0];
      float gf = acc[1][j] + bc1[1];
      float gg = acc[2][j] + bc1[2];
      float go = acc[3][j] + bc1[3];
      float cn = fsig(gf) * cs1[j] + fsig(gi) * ftanh(gg);
      cs1[j] = cn;
      hv[j] = f2bf(fsig(go) * ftanh(cn));
    }
    LGKM_BAR;   // all reads of H1(t-1)/XB(t) complete
#pragma unroll
    for (int j = 0; j < 4; ++j) {
      int r = lg * 4 + j;
      H1s[(r * 128 + 16 * wid + lr) ^ ((r & 7) << 3)] = hv[j];
    }
    LGKM_BAR;   // H1(t) visible

    // ---- cell2: A = [h1 | h2]; h1-half VGPR weights, h2-half LDS ----
    f32x4 acd[4] = {};
#pragma unroll
    for (int kf = 0; kf < 4; ++kf) {
      int kg = kf * 4 + lg;
      bf16x8 A = *(const bf16x8*)&H1s[(lr * 128 + kg * 8) ^ ((lr & 7) << 3)];
#pragma unroll
      for (int g = 0; g < 4; ++g) acd[g] = MFMA16(A, wgt2v[g][kf], acd[g]);
    }
#pragma unroll
    for (int kf = 0; kf < 4; ++kf) {
      int kg = kf * 4 + lg;
      bf16x8 A = *(const bf16x8*)&H2s[(lr * 128 + kg * 8) ^ ((lr & 7) << 3)];
#pragma unroll
      for (int g = 0; g < 4; ++g) {
        bf16x8 B = *(const bf16x8*)&Wl[(size_t)(((wid * 4 + g) * 4 + kf) * 512) + lane * 8];
        acd[g] = MFMA16(A, B, acd[g]);
      }
    }
#pragma unroll
    for (int j = 0; j < 4; ++j) {
      float gi = acd[0][j] + bc2[0];
      float gf = acd[1][j] + bc2[1];
      float gg = acd[2][j] + bc2[2];
      float go = acd[3][j] + bc2[3];
      float cn = fsig(gf) * cs2[j] + fsig(gi) * ftanh(gg);
      cs2[j] = cn;
      hv[j] = f2bf(fsig(go) * ftanh(cn));
    }
    LGKM_BAR;   // all reads of H2(t-1)/H1(t) complete
#pragma unroll
    for (int j = 0; j < 4; ++j) {
      int r = lg * 4 + j;
      H2s[(r * 128 + 16 * wid + lr) ^ ((r & 7) << 3)] = hv[j];
    }
    if (ld) *(u16x4*)&XBs[(r5 * 128 + c5) ^ ((r5 & 7) << 3)] = xn;
    LGKM_BAR;   // H2(t), x(t+1) visible
  }

  if (!last) {
    // ---- persist state ----
    int sw = (r5 * 128 + c5) ^ ((r5 & 7) << 3);
    *(u16x4*)(wsu + STH1_U + (size_t)(b0 + r5) * 128 + c5) = *(const u16x4*)&H1s[sw];
    *(u16x4*)(wsu + STH2_U + (size_t)(b0 + r5) * 128 + c5) = *(const u16x4*)&H2s[sw];
#pragma unroll
    for (int j = 0; j < 4; ++j) {
      wsf[C1_F + (size_t)(b0 + lg * 4 + j) * 128 + 16 * wid + lr] = cs1[j];
      wsf[C2_F + (size_t)(b0 + lg * 4 + j) * 128 + 16 * wid + lr] = cs2[j];
    }
  } else {
    // ---- head: Y1 -> XBs, Y2 -> XBs|H1s, Y3 -> out ----
    {
      f32x4 y1 = {};
#pragma unroll
      for (int kf = 0; kf < 4; ++kf) {
        int kg = kf * 4 + lg;
        bf16x8 A = *(const bf16x8*)&H2s[(lr * 128 + kg * 8) ^ ((lr & 7) << 3)];
        bf16x8 B = *(const bf16x8*)(wsu + WO1_U + (size_t)(((wid * 4 + kf)) * 512) + lane * 8);
        y1 = MFMA16(A, B, y1);
      }
      float bo1 = b_out1[wid * 16 + lr];
      LGKM_BAR;
#pragma unroll
      for (int j = 0; j < 4; ++j) {
        int r = lg * 4 + j;
        XBs[(r * 128 + 16 * wid + lr) ^ ((r & 7) << 3)] = f2bf(fmaxf(y1[j] + bo1, 0.f));
      }
      LGKM_BAR;
    }
    {
      f32x4 y2[2] = {};
#pragma unroll
      for (int kf = 0; kf < 4; ++kf) {
        int kg = kf * 4 + lg;
        bf16x8 A = *(const bf16x8*)&XBs[(lr * 128 + kg * 8) ^ ((lr & 7) << 3)];
#pragma unroll
        for (int n = 0; n < 2; ++n) {
          bf16x8 B = *(const bf16x8*)(wsu + WO2_U + (size_t)((((2 * wid + n) * 4 + kf)) * 512) + lane * 8);
          y2[n] = MFMA16(A, B, y2[n]);
        }
      }
      LGKM_BAR;   // Y1 reads done before overwrite
#pragma unroll
      for (int n = 0; n < 2; ++n)
#pragma unroll
        for (int j = 0; j < 4; ++j) {
          int c = (2 * wid + n) * 16 + lr;
          float v = fmaxf(y2[n][j] + b_out2[c], 0.f);
          u16* buf = (c < 128) ? XBs : H1s;
          int cc = c & 127, r = lg * 4 + j;
          buf[(r * 128 + cc) ^ ((r & 7) << 3)] = f2bf(v);
        }
      LGKM_BAR;
    }
    if (wid < 2) {
      f32x4 y3 = {};
#pragma unroll
      for (int kf = 0; kf < 8; ++kf) {
        const u16* ab = (kf < 4) ? XBs : H1s;
        int kg = (kf & 3) * 4 + lg;
        bf16x8 A = *(const bf16x8*)&ab[(lr * 128 + kg * 8) ^ ((lr & 7) << 3)];
        bf16x8 B = *(const bf16x8*)(wsu + WO3_U + (size_t)(((wid * 8 + kf)) * 512) + lane * 8);
        y3 = MFMA16(A, B, y3);
      }
      float bo3 = b_out3[wid * 16 + lr];
#pragma unroll
      for (int j = 0; j < 4; ++j)
        out[(size_t)(b0 + lg * 4 + j) * 32 + wid * 16 + lr] = y3[j] + bo3;
    }
  }
}

// ======================= host ==============================================
extern "C" void kernel_launch(void* const* d_in, const int* in_sizes, int n_in,
                              void* d_out, int out_size, void* d_ws, size_t ws_size,
                              hipStream_t stream) {
  (void)in_sizes; (void)n_in; (void)out_size; (void)ws_size;
  const float* seq    = (const float*)d_in[0];
  const float* h1     = (const float*)d_in[1];
  const float* c1     = (const float*)d_in[2];
  const float* h2     = (const float*)d_in[3];
  const float* c2     = (const float*)d_in[4];
  const float* W_in1  = (const float*)d_in[5];
  const float* b_in1  = (const float*)d_in[6];
  const float* W_in2  = (const float*)d_in[7];
  const float* b_in2  = (const float*)d_in[8];
  const float* W_in3  = (const float*)d_in[9];
  const float* b_in3  = (const float*)d_in[10];
  const float* Wih1   = (const float*)d_in[11];
  const float* Whh1   = (const float*)d_in[12];
  const float* bih1   = (const float*)d_in[13];
  const float* bhh1   = (const float*)d_in[14];
  const float* Wih2   = (const float*)d_in[15];
  const float* Whh2   = (const float*)d_in[16];
  const float* bih2   = (const float*)d_in[17];
  const float* bhh2   = (const float*)d_in[18];
  const float* W_out1 = (const float*)d_in[19];
  const float* b_out1 = (const float*)d_in[20];
  const float* W_out2 = (const float*)d_in[21];
  const float* b_out2 = (const float*)d_in[22];
  const float* W_out3 = (const float*)d_in[23];
  const float* b_out3 = (const float*)d_in[24];
  u16* wsu = (u16*)d_ws;
  float* out = (float*)d_out;

  hipLaunchKernelGGL(prep_kernel, dim3(512), dim3(256), 0, stream,
                     Wih1, Whh1, bih1, bhh1, Wih2, Whh2, bih2, bhh2,
                     W_in1, W_in2, W_in3, W_out1, W_out2, W_out3,
                     h1, h2, c1, c2, wsu);
  for (int k = 0; k < NCH; ++k) {
    hipLaunchKernelGGL(fc_chunk, dim3(2048), dim3(256), 0, stream,
                       seq, b_in1, b_in2, b_in3, wsu, k * TC);
    hipLaunchKernelGGL(scan_chunk, dim3(256), dim3(512), 0, stream,
                       wsu, out, b_out1, b_out2, b_out3, (k == NCH - 1) ? 1 : 0);
  }
}

// Round 6
// 1608.580 us; speedup vs baseline: 35.2903x; 1.0207x over previous
//
#include <hip/hip_runtime.h>

// ---------------------------------------------------------------------------
// R6: resident-weight LSTM scan, decoupled fc_in.
//  - fc_chunk: batched GEMM computes x = fc_in(seq) for a 32-step t-chunk
//    into ws XBUF (bf16).  2048 blocks x 256 thr.
//  - scan_chunk: 256 blocks x 512 thr, 16 batch rows each. Cell weights:
//    wgt1[4][8] + wgt2v[4][4] in VGPRs (192/wave) PINNED via opaque asm so
//    the compiler cannot rematerialize the loads inside the loop (R5 bug:
//    VGPR_Count=128 proved weights were re-loaded every step). Cell2 h2-half
//    B-frags in LDS (128 KB). H1/H2 double-buffered -> 2 lgkm barriers/step.
//  ws requirement: ~42 MB (XBUF 32 MB @ byte 8388608).
// ---------------------------------------------------------------------------

typedef unsigned short u16;
typedef short bf16x8 __attribute__((ext_vector_type(8)));
typedef float f32x4 __attribute__((ext_vector_type(4)));
typedef unsigned short u16x4 __attribute__((ext_vector_type(4)));

#define MFMA16(a, b, c) __builtin_amdgcn_mfma_f32_16x16x32_bf16((a), (b), (c), 0, 0, 0)

#define GLOAD_LDS(gp, lp) __builtin_amdgcn_global_load_lds( \
    (const __attribute__((address_space(1))) unsigned int*)(const void*)(gp), \
    (__attribute__((address_space(3))) unsigned int*)(void*)(lp), 16, 0, 0)

// raw barrier with lgkm-only drain (keeps x-prefetch vmem in flight)
#define LGKM_BAR do { \
  asm volatile("s_waitcnt lgkmcnt(0)" ::: "memory"); \
  __builtin_amdgcn_sched_barrier(0); \
  __builtin_amdgcn_s_barrier(); \
  __builtin_amdgcn_sched_barrier(0); \
} while (0)

__device__ __forceinline__ u16 f2bf(float f) {
  union { float f; unsigned u; } v; v.f = f;
  return (u16)((v.u + 0x7FFFu + ((v.u >> 16) & 1u)) >> 16);  // RNE
}
__device__ __forceinline__ float fsig(float x) { return 1.0f / (1.0f + __expf(-x)); }
__device__ __forceinline__ float ftanh(float x) { return 2.0f / (1.0f + __expf(-2.0f * x)) - 1.0f; }

// ---- ws layout (u16 / f32 indices) ---------------------------------------
#define WC1_U   0         // 256 frags: ((w*4+g)*8+kf)*512
#define WC2V_U  131072    // 128 frags: ((w*4+g)*4+kf)*512 ; Wih2
#define WC2L_U  196608    // 128 frags: Whh2
#define W1_U    262144
#define W2_U    278528
#define W3_U    311296
#define WO1_U   327680
#define WO2_U   344064
#define WO3_U   376832
#define BS1_F   192512
#define BS2_F   193024
#define STH1_U  393216
#define STH2_U  917504
#define C1_F    720896
#define C2_F    1245184
#define XB_U    4194304   // bf16[32][4096][128] x chunk buffer (byte 8388608)
#define TC      32
#define NCH     8

// ======================= prep ==============================================
__global__ void prep_kernel(const float* __restrict__ Wih1, const float* __restrict__ Whh1,
                            const float* __restrict__ bih1, const float* __restrict__ bhh1,
                            const float* __restrict__ Wih2, const float* __restrict__ Whh2,
                            const float* __restrict__ bih2, const float* __restrict__ bhh2,
                            const float* __restrict__ W_in1, const float* __restrict__ W_in2,
                            const float* __restrict__ W_in3,
                            const float* __restrict__ W_out1, const float* __restrict__ W_out2,
                            const float* __restrict__ W_out3,
                            const float* __restrict__ h1_in, const float* __restrict__ h2_in,
                            const float* __restrict__ c1_in, const float* __restrict__ c2_in,
                            u16* __restrict__ wsu) {
  float* wsf = (float*)wsu;
  const int N_total = 2490368;
  int stride = gridDim.x * blockDim.x;
  for (int idx = blockIdx.x * blockDim.x + threadIdx.x; idx < N_total; idx += stride) {
    if (idx < 385024) {
      int within = idx & 511;
      int frag = (idx >> 9);
      int lane = within >> 3, e = within & 7;
      int lr = lane & 15, lg = lane >> 4;
      int k8 = lg * 8 + e;
      float v;
      if (idx < 131072) {                     // WC1
        int kf = frag & 7, g = (frag >> 3) & 3, w = frag >> 5;
        int row = g * 128 + w * 16 + lr;
        int k = kf * 32 + k8;
        v = (k < 128) ? Wih1[row * 128 + k] : Whh1[row * 128 + (k - 128)];
      } else if (idx < 196608) {              // WC2V: Wih2
        int f = frag - 256;
        int kf = f & 3, g = (f >> 2) & 3, w = f >> 4;
        v = Wih2[(g * 128 + w * 16 + lr) * 128 + kf * 32 + k8];
      } else if (idx < 262144) {              // WC2L: Whh2
        int f = frag - 384;
        int kf = f & 3, g = (f >> 2) & 3, w = f >> 4;
        v = Whh2[(g * 128 + w * 16 + lr) * 128 + kf * 32 + k8];
      } else if (idx < 278528) {              // W1
        int f = frag - 512; int kf = f & 1, n = f >> 1;
        v = W_in1[(n * 16 + lr) * 64 + kf * 32 + k8];
      } else if (idx < 311296) {              // W2
        int f = frag - 544; int kf = f & 7, n = f >> 3;
        v = W_in2[(n * 16 + lr) * 256 + kf * 32 + k8];
      } else if (idx < 327680) {              // W3
        int f = frag - 608; int kf = f & 3, n = f >> 2;
        v = W_in3[(n * 16 + lr) * 128 + kf * 32 + k8];
      } else if (idx < 344064) {              // WO1
        int f = frag - 640; int kf = f & 3, n = f >> 2;
        v = W_out1[(n * 16 + lr) * 128 + kf * 32 + k8];
      } else if (idx < 376832) {              // WO2
        int f = frag - 672; int kf = f & 3, n = f >> 2;
        v = W_out2[(n * 16 + lr) * 128 + kf * 32 + k8];
      } else {                                // WO3
        int f = frag - 736; int kf = f & 7, n = f >> 3;
        v = W_out3[(n * 16 + lr) * 256 + kf * 32 + k8];
      }
      wsu[idx] = f2bf(v);
    } else if (idx < 385536) {
      int i = idx - 385024; wsf[BS1_F + i] = bih1[i] + bhh1[i];
    } else if (idx < 386048) {
      int i = idx - 385536; wsf[BS2_F + i] = bih2[i] + bhh2[i];
    } else if (idx < 393216) {
      // pad
    } else if (idx < 917504) {
      int i = idx - 393216; wsu[STH1_U + i] = f2bf(h1_in[i]);
    } else if (idx < 1441792) {
      int i = idx - 917504; wsu[STH2_U + i] = f2bf(h2_in[i]);
    } else if (idx < 1966080) {
      int i = idx - 1441792; wsf[C1_F + i] = c1_in[i];
    } else {
      int i = idx - 1966080; wsf[C2_F + i] = c2_in[i];
    }
  }
}

// ======================= fc_in chunk =======================================
__global__ __launch_bounds__(256, 2)
void fc_chunk(const float* __restrict__ seq,
              const float* __restrict__ b_in1, const float* __restrict__ b_in2,
              const float* __restrict__ b_in3,
              u16* __restrict__ wsu, int t0) {
  __shared__ u16 SEQs[4096];
  __shared__ u16 F1s[16384];
  __shared__ u16 F2s[8192];
  const int tid = threadIdx.x;
  const int wid = tid >> 6, lane = tid & 63;
  const int lr = lane & 15, lg = lane >> 4;
  const int bid = blockIdx.x;

#pragma unroll
  for (int i = 0; i < 4; ++i) {
    int f = i * 1024 + tid * 4;
    int rho = f >> 6, k = f & 63;
    int b = bid * 2 + (rho >> 5), tl = rho & 31;
    float4 v = *(const float4*)(seq + ((size_t)b * 256 + t0 + tl) * 64 + k);
    u16x4 o = { f2bf(v.x), f2bf(v.y), f2bf(v.z), f2bf(v.w) };
    *(u16x4*)&SEQs[(rho * 64 + k) ^ ((rho & 7) << 3)] = o;
  }
  __syncthreads();

  {
    f32x4 a1[4][4] = {};
#pragma unroll
    for (int kf = 0; kf < 2; ++kf) {
      bf16x8 A[4];
#pragma unroll
      for (int rt = 0; rt < 4; ++rt) {
        int r = 16 * rt + lr;
        A[rt] = *(const bf16x8*)&SEQs[(r * 64 + (kf * 4 + lg) * 8) ^ ((r & 7) << 3)];
      }
#pragma unroll
      for (int n = 0; n < 4; ++n) {
        bf16x8 B = *(const bf16x8*)(wsu + W1_U + (size_t)(((4 * wid + n) * 2 + kf) * 512) + lane * 8);
#pragma unroll
        for (int rt = 0; rt < 4; ++rt) a1[rt][n] = MFMA16(A[rt], B, a1[rt][n]);
      }
    }
#pragma unroll
    for (int n = 0; n < 4; ++n) {
      float bb = b_in1[(4 * wid + n) * 16 + lr];
#pragma unroll
      for (int rt = 0; rt < 4; ++rt)
#pragma unroll
        for (int j = 0; j < 4; ++j) {
          int r = 16 * rt + lg * 4 + j, c = (4 * wid + n) * 16 + lr;
          F1s[(r * 256 + c) ^ ((r & 7) << 3)] = f2bf(fmaxf(a1[rt][n][j] + bb, 0.f));
        }
    }
  }
  __syncthreads();

  {
    f32x4 a2[4][2] = {};
#pragma unroll
    for (int kf = 0; kf < 8; ++kf) {
      bf16x8 A[4];
#pragma unroll
      for (int rt = 0; rt < 4; ++rt) {
        int r = 16 * rt + lr;
        A[rt] = *(const bf16x8*)&F1s[(r * 256 + (kf * 4 + lg) * 8) ^ ((r & 7) << 3)];
      }
#pragma unroll
      for (int n = 0; n < 2; ++n) {
        bf16x8 B = *(const bf16x8*)(wsu + W2_U + (size_t)(((2 * wid + n) * 8 + kf) * 512) + lane * 8);
#pragma unroll
        for (int rt = 0; rt < 4; ++rt) a2[rt][n] = MFMA16(A[rt], B, a2[rt][n]);
      }
    }
#pragma unroll
    for (int n = 0; n < 2; ++n) {
      float bb = b_in2[(2 * wid + n) * 16 + lr];
#pragma unroll
      for (int rt = 0; rt < 4; ++rt)
#pragma unroll
        for (int j = 0; j < 4; ++j) {
          int r = 16 * rt + lg * 4 + j, c = (2 * wid + n) * 16 + lr;
          F2s[(r * 128 + c) ^ ((r & 7) << 3)] = f2bf(fmaxf(a2[rt][n][j] + bb, 0.f));
        }
    }
  }
  __syncthreads();

  {
    f32x4 a3[4][2] = {};
#pragma unroll
    for (int kf = 0; kf < 4; ++kf) {
      bf16x8 A[4];
#pragma unroll
      for (int rt = 0; rt < 4; ++rt) {
        int r = 16 * rt + lr;
        A[rt] = *(const bf16x8*)&F2s[(r * 128 + (kf * 4 + lg) * 8) ^ ((r & 7) << 3)];
      }
#pragma unroll
      for (int n = 0; n < 2; ++n) {
        bf16x8 B = *(const bf16x8*)(wsu + W3_U + (size_t)(((2 * wid + n) * 4 + kf) * 512) + lane * 8);
#pragma unroll
        for (int rt = 0; rt < 4; ++rt) a3[rt][n] = MFMA16(A[rt], B, a3[rt][n]);
      }
    }
#pragma unroll
    for (int n = 0; n < 2; ++n) {
      float bb = b_in3[(2 * wid + n) * 16 + lr];
#pragma unroll
      for (int rt = 0; rt < 4; ++rt)
#pragma unroll
        for (int j = 0; j < 4; ++j) {
          int rho = 16 * rt + lg * 4 + j;
          int b = bid * 2 + (rho >> 5), tl = rho & 31;
          int c = (2 * wid + n) * 16 + lr;
          wsu[XB_U + ((size_t)tl * 4096 + b) * 128 + c] = f2bf(fmaxf(a3[rt][n][j] + bb, 0.f));
        }
    }
  }
}

// ======================= scan chunk ========================================
__global__ __launch_bounds__(512, 2)
void scan_chunk(u16* __restrict__ wsu, float* __restrict__ out,
                const float* __restrict__ b_out1, const float* __restrict__ b_out2,
                const float* __restrict__ b_out3, int last) {
  __shared__ u16 Wl[65536];                       // 128 KB: Whh2 B-frags
  __shared__ u16 XBs[2048];                       // [16][128]
  __shared__ u16 H1d[2][2048], H2d[2][2048];      // double-buffered h tiles

  float* wsf = (float*)wsu;
  const int tid = threadIdx.x;
  const int wid = tid >> 6, lane = tid & 63;
  const int lr = lane & 15, lg = lane >> 4;
  const int b0 = blockIdx.x * 16;
  const int r5 = tid >> 5, c5 = (tid & 31) * 4;

  // ---- register-resident weights (then PINNED below) ----
  bf16x8 wgt1[4][8], wgt2v[4][4];
#pragma unroll
  for (int g = 0; g < 4; ++g) {
#pragma unroll
    for (int kf = 0; kf < 8; ++kf)
      wgt1[g][kf] = *(const bf16x8*)(wsu + WC1_U + (size_t)(((wid * 4 + g) * 8 + kf) * 512) + lane * 8);
#pragma unroll
    for (int kf = 0; kf < 4; ++kf)
      wgt2v[g][kf] = *(const bf16x8*)(wsu + WC2V_U + (size_t)(((wid * 4 + g) * 4 + kf) * 512) + lane * 8);
  }
  // PIN: opaque asm makes the values non-rematerializable -> they must stay
  // in VGPRs across the whole scan loop (R5's compiler re-loaded them/step).
#pragma unroll
  for (int g = 0; g < 4; ++g) {
#pragma unroll
    for (int kf = 0; kf < 8; ++kf) asm volatile("" : "+v"(wgt1[g][kf]));
#pragma unroll
    for (int kf = 0; kf < 4; ++kf) asm volatile("" : "+v"(wgt2v[g][kf]));
  }

  // ---- Whh2 -> Wl LDS ----
#pragma unroll
  for (int i = 0; i < 16; ++i)
    GLOAD_LDS(wsu + WC2L_U + wid * 8192 + i * 512 + lane * 8, &Wl[wid * 8192 + i * 512]);

  // ---- state ----
  u16x4 hh1 = *(const u16x4*)(wsu + STH1_U + (size_t)(b0 + r5) * 128 + c5);
  u16x4 hh2 = *(const u16x4*)(wsu + STH2_U + (size_t)(b0 + r5) * 128 + c5);
  u16x4 xq  = *(const u16x4*)(wsu + XB_U + ((size_t)0 * 4096 + b0 + r5) * 128 + c5);
  float cs1[4], cs2[4], bc1[4], bc2[4];
#pragma unroll
  for (int j = 0; j < 4; ++j) {
    cs1[j] = wsf[C1_F + (size_t)(b0 + lg * 4 + j) * 128 + 16 * wid + lr];
    cs2[j] = wsf[C2_F + (size_t)(b0 + lg * 4 + j) * 128 + 16 * wid + lr];
  }
#pragma unroll
  for (int g = 0; g < 4; ++g) {
    bc1[g] = wsf[BS1_F + g * 128 + 16 * wid + lr];
    bc2[g] = wsf[BS2_F + g * 128 + 16 * wid + lr];
  }
  {
    int sw = (r5 * 128 + c5) ^ ((r5 & 7) << 3);
    *(u16x4*)&H1d[0][sw] = hh1;
    *(u16x4*)&H2d[0][sw] = hh2;
    *(u16x4*)&XBs[sw] = xq;
  }
  __syncthreads();   // full sync (drains Wl gload_lds too)

  // ================= 32-step scan: 2 barriers/step =================
#pragma unroll 2
  for (int tl = 0; tl < TC; ++tl) {
    const int p = tl & 1, q = p ^ 1;
    const bool ld = (tl < TC - 1);
    u16x4 xn;
    if (ld) xn = *(const u16x4*)(wsu + XB_U + ((size_t)(tl + 1) * 4096 + b0 + r5) * 128 + c5);

    // ---- phase 1: cell1 (A = [x | h1(t-1)]), all-VGPR weights ----
    f32x4 acc[4] = {};
#pragma unroll
    for (int kf = 0; kf < 8; ++kf) {
      const u16* ab = (kf < 4) ? XBs : H1d[p];
      int kg = (kf & 3) * 4 + lg;
      bf16x8 A = *(const bf16x8*)&ab[(lr * 128 + kg * 8) ^ ((lr & 7) << 3)];
#pragma unroll
      for (int g = 0; g < 4; ++g) acc[g] = MFMA16(A, wgt1[g][kf], acc[g]);
    }
    u16 hv[4];
#pragma unroll
    for (int j = 0; j < 4; ++j) {
      float gi = acc[0][j] + bc1[0];
      float gf = acc[1][j] + bc1[1];
      float gg = acc[2][j] + bc1[2];
      float go = acc[3][j] + bc1[3];
      float cn = fsig(gf) * cs1[j] + fsig(gi) * ftanh(gg);
      cs1[j] = cn;
      hv[j] = f2bf(fsig(go) * ftanh(cn));
    }
#pragma unroll
    for (int j = 0; j < 4; ++j) {
      int r = lg * 4 + j;
      H1d[q][(r * 128 + 16 * wid + lr) ^ ((r & 7) << 3)] = hv[j];   // other buffer: no pre-barrier
    }
    LGKM_BAR;   // H1(t) visible; phase-1 reads of XBs/H1d[p] all complete

    // ---- phase 2: cell2 (A = [h1(t) | h2(t-1)]) ----
    f32x4 acd[4] = {};
#pragma unroll
    for (int kf = 0; kf < 4; ++kf) {
      int kg = kf * 4 + lg;
      bf16x8 A = *(const bf16x8*)&H1d[q][(lr * 128 + kg * 8) ^ ((lr & 7) << 3)];
#pragma unroll
      for (int g = 0; g < 4; ++g) acd[g] = MFMA16(A, wgt2v[g][kf], acd[g]);
    }
#pragma unroll
    for (int kf = 0; kf < 4; ++kf) {
      int kg = kf * 4 + lg;
      bf16x8 A = *(const bf16x8*)&H2d[p][(lr * 128 + kg * 8) ^ ((lr & 7) << 3)];
#pragma unroll
      for (int g = 0; g < 4; ++g) {
        bf16x8 B = *(const bf16x8*)&Wl[(size_t)(((wid * 4 + g) * 4 + kf) * 512) + lane * 8];
        acd[g] = MFMA16(A, B, acd[g]);
      }
    }
#pragma unroll
    for (int j = 0; j < 4; ++j) {
      float gi = acd[0][j] + bc2[0];
      float gf = acd[1][j] + bc2[1];
      float gg = acd[2][j] + bc2[2];
      float go = acd[3][j] + bc2[3];
      float cn = fsig(gf) * cs2[j] + fsig(gi) * ftanh(gg);
      cs2[j] = cn;
      hv[j] = f2bf(fsig(go) * ftanh(cn));
    }
#pragma unroll
    for (int j = 0; j < 4; ++j) {
      int r = lg * 4 + j;
      H2d[q][(r * 128 + 16 * wid + lr) ^ ((r & 7) << 3)] = hv[j];
    }
    if (ld) *(u16x4*)&XBs[(r5 * 128 + c5) ^ ((r5 & 7) << 3)] = xn;  // phase-1 XB reads done (BAR1)
    LGKM_BAR;   // H2(t), x(t+1) visible
  }
  // TC even -> final state in H1d[0]/H2d[0]

  if (!last) {
    int sw = (r5 * 128 + c5) ^ ((r5 & 7) << 3);
    *(u16x4*)(wsu + STH1_U + (size_t)(b0 + r5) * 128 + c5) = *(const u16x4*)&H1d[0][sw];
    *(u16x4*)(wsu + STH2_U + (size_t)(b0 + r5) * 128 + c5) = *(const u16x4*)&H2d[0][sw];
#pragma unroll
    for (int j = 0; j < 4; ++j) {
      wsf[C1_F + (size_t)(b0 + lg * 4 + j) * 128 + 16 * wid + lr] = cs1[j];
      wsf[C2_F + (size_t)(b0 + lg * 4 + j) * 128 + 16 * wid + lr] = cs2[j];
    }
  } else {
    // ---- head: Y1 -> XBs, Y2 -> XBs|H1d[0], Y3 -> out ----
    {
      f32x4 y1 = {};
#pragma unroll
      for (int kf = 0; kf < 4; ++kf) {
        int kg = kf * 4 + lg;
        bf16x8 A = *(const bf16x8*)&H2d[0][(lr * 128 + kg * 8) ^ ((lr & 7) << 3)];
        bf16x8 B = *(const bf16x8*)(wsu + WO1_U + (size_t)((wid * 4 + kf) * 512) + lane * 8);
        y1 = MFMA16(A, B, y1);
      }
      float bo1 = b_out1[wid * 16 + lr];
      LGKM_BAR;
#pragma unroll
      for (int j = 0; j < 4; ++j) {
        int r = lg * 4 + j;
        XBs[(r * 128 + 16 * wid + lr) ^ ((r & 7) << 3)] = f2bf(fmaxf(y1[j] + bo1, 0.f));
      }
      LGKM_BAR;
    }
    {
      f32x4 y2[2] = {};
#pragma unroll
      for (int kf = 0; kf < 4; ++kf) {
        int kg = kf * 4 + lg;
        bf16x8 A = *(const bf16x8*)&XBs[(lr * 128 + kg * 8) ^ ((lr & 7) << 3)];
#pragma unroll
        for (int n = 0; n < 2; ++n) {
          bf16x8 B = *(const bf16x8*)(wsu + WO2_U + (size_t)(((2 * wid + n) * 4 + kf) * 512) + lane * 8);
          y2[n] = MFMA16(A, B, y2[n]);
        }
      }
      LGKM_BAR;   // Y1 reads done before overwrite
#pragma unroll
      for (int n = 0; n < 2; ++n)
#pragma unroll
        for (int j = 0; j < 4; ++j) {
          int c = (2 * wid + n) * 16 + lr;
          float v = fmaxf(y2[n][j] + b_out2[c], 0.f);
          u16* buf = (c < 128) ? XBs : &H1d[0][0];
          int cc = c & 127, r = lg * 4 + j;
          buf[(r * 128 + cc) ^ ((r & 7) << 3)] = f2bf(v);
        }
      LGKM_BAR;
    }
    if (wid < 2) {
      f32x4 y3 = {};
#pragma unroll
      for (int kf = 0; kf < 8; ++kf) {
        const u16* ab = (kf < 4) ? XBs : &H1d[0][0];
        int kg = (kf & 3) * 4 + lg;
        bf16x8 A = *(const bf16x8*)&ab[(lr * 128 + kg * 8) ^ ((lr & 7) << 3)];
        bf16x8 B = *(const bf16x8*)(wsu + WO3_U + (size_t)((wid * 8 + kf) * 512) + lane * 8);
        y3 = MFMA16(A, B, y3);
      }
      float bo3 = b_out3[wid * 16 + lr];
#pragma unroll
      for (int j = 0; j < 4; ++j)
        out[(size_t)(b0 + lg * 4 + j) * 32 + wid * 16 + lr] = y3[j] + bo3;
    }
  }
}

// ======================= host ==============================================
extern "C" void kernel_launch(void* const* d_in, const int* in_sizes, int n_in,
                              void* d_out, int out_size, void* d_ws, size_t ws_size,
                              hipStream_t stream) {
  (void)in_sizes; (void)n_in; (void)out_size; (void)ws_size;
  const float* seq    = (const float*)d_in[0];
  const float* h1     = (const float*)d_in[1];
  const float* c1     = (const float*)d_in[2];
  const float* h2     = (const float*)d_in[3];
  const float* c2     = (const float*)d_in[4];
  const float* W_in1  = (const float*)d_in[5];
  const float* b_in1  = (const float*)d_in[6];
  const float* W_in2  = (const float*)d_in[7];
  const float* b_in2  = (const float*)d_in[8];
  const float* W_in3  = (const float*)d_in[9];
  const float* b_in3  = (const float*)d_in[10];
  const float* Wih1   = (const float*)d_in[11];
  const float* Whh1   = (const float*)d_in[12];
  const float* bih1   = (const float*)d_in[13];
  const float* bhh1   = (const float*)d_in[14];
  const float* Wih2   = (const float*)d_in[15];
  const float* Whh2   = (const float*)d_in[16];
  const float* bih2   = (const float*)d_in[17];
  const float* bhh2   = (const float*)d_in[18];
  const float* W_out1 = (const float*)d_in[19];
  const float* b_out1 = (const float*)d_in[20];
  const float* W_out2 = (const float*)d_in[21];
  const float* b_out2 = (const float*)d_in[22];
  const float* W_out3 = (const float*)d_in[23];
  const float* b_out3 = (const float*)d_in[24];
  u16* wsu = (u16*)d_ws;
  float* out = (float*)d_out;

  hipLaunchKernelGGL(prep_kernel, dim3(512), dim3(256), 0, stream,
                     Wih1, Whh1, bih1, bhh1, Wih2, Whh2, bih2, bhh2,
                     W_in1, W_in2, W_in3, W_out1, W_out2, W_out3,
                     h1, h2, c1, c2, wsu);
  for (int k = 0; k < NCH; ++k) {
    hipLaunchKernelGGL(fc_chunk, dim3(2048), dim3(256), 0, stream,
                       seq, b_in1, b_in2, b_in3, wsu, k * TC);
    hipLaunchKernelGGL(scan_chunk, dim3(256), dim3(512), 0, stream,
                       wsu, out, b_out1, b_out2, b_out3, (k == NCH - 1) ? 1 : 0);
  }
}